// Round 1
// baseline (429.039 us; speedup 1.0000x reference)
//
#include <hip/hip_runtime.h>
#include <cmath>

#define B_ 8
#define S_ 512
#define D_ 512
#define H_ 1024
#define E_ 8
#define NT_ (B_*S_)   // 4096 tokens
#define TM 16         // tokens per expert tile

// ---------------- gating: one wave (64 lanes) per token ----------------
__global__ __launch_bounds__(256) void gating_kernel(
    const float* __restrict__ x, const int* __restrict__ mask,
    const float* __restrict__ wg, int* __restrict__ counts,
    int* __restrict__ lists, float* __restrict__ gvals)
{
    const int wave = threadIdx.x >> 6;
    const int lane = threadIdx.x & 63;
    const int t = blockIdx.x * 4 + wave;
    const float* xr = x + (size_t)t * D_;
    float acc[E_];
#pragma unroll
    for (int e = 0; e < E_; ++e) acc[e] = 0.f;
    for (int d = lane; d < D_; d += 64) {
        const float xv = xr[d];
        const float* wr = wg + (size_t)d * E_;
#pragma unroll
        for (int e = 0; e < E_; ++e) acc[e] += xv * wr[e];
    }
#pragma unroll
    for (int e = 0; e < E_; ++e) {
        float v = acc[e];
#pragma unroll
        for (int off = 32; off > 0; off >>= 1) v += __shfl_down(v, off, 64);
        acc[e] = v;
    }
    if (lane == 0 && mask[t] != 0) {
        // top-2 (first-occurrence tie-break matches jax top_k)
        int i0 = 0; float v0 = acc[0];
#pragma unroll
        for (int e = 1; e < E_; ++e) if (acc[e] > v0) { v0 = acc[e]; i0 = e; }
        int i1 = -1; float v1 = -INFINITY;
#pragma unroll
        for (int e = 0; e < E_; ++e) if (e != i0 && acc[e] > v1) { v1 = acc[e]; i1 = e; }
        const float ex = __expf(v1 - v0);
        const float denom = 1.f + ex;
        const float g0 = 1.f / denom;
        const float g1 = ex / denom;
        const int p0 = atomicAdd(&counts[i0], 1);
        lists[i0 * NT_ + p0] = t; gvals[i0 * NT_ + p0] = g0;
        const int p1 = atomicAdd(&counts[i1], 1);
        lists[i1 * NT_ + p1] = t; gvals[i1 * NT_ + p1] = g1;
    }
}

// ---------------- residual init: out = x ----------------
__global__ __launch_bounds__(256) void init_out_kernel(
    const float* __restrict__ x, float* __restrict__ out)
{
    const size_t i = (size_t)blockIdx.x * blockDim.x + threadIdx.x;
    ((float4*)out)[i] = ((const float4*)x)[i];
}

// ---------------- fused 2-stage expert MLP over a 16-token tile ----------------
// Stage1: Hs[16][1024] = relu(Xs[16][512] @ W1[e] + b1[e])
// Stage2: out[tok] += gate * (Hs @ W2[e] + b2[e])   (fp32 atomics)
__global__ __launch_bounds__(256) void expert_kernel(
    const float* __restrict__ x,
    const float* __restrict__ W1, const float* __restrict__ b1,
    const float* __restrict__ W2, const float* __restrict__ b2,
    const int* __restrict__ counts, const int* __restrict__ lists,
    const float* __restrict__ gvals, float* __restrict__ out)
{
    __shared__ float Xs[TM][D_];    // 32 KB
    __shared__ float Hs[TM][H_];    // 64 KB
    __shared__ int   tks[TM];
    __shared__ float gs[TM];

    const int e  = blockIdx.y;
    const int n  = counts[e];
    const int t0 = blockIdx.x * TM;
    if (t0 >= n) return;
    const int tid  = threadIdx.x;
    const int mact = min(TM, n - t0);

    if (tid < TM) {
        if (tid < mact) {
            tks[tid] = lists[e * NT_ + t0 + tid];
            gs[tid]  = gvals[e * NT_ + t0 + tid];
        } else { tks[tid] = 0; gs[tid] = 0.f; }
    }
    __syncthreads();

    // load X tile (zero-fill dead rows)
    for (int idx = tid; idx < TM * (D_ / 4); idx += 256) {
        const int m = idx >> 7;
        const int c = idx & 127;
        float4 v = make_float4(0.f, 0.f, 0.f, 0.f);
        if (m < mact) v = ((const float4*)(x + (size_t)tks[m] * D_))[c];
        ((float4*)&Xs[m][0])[c] = v;
    }
    __syncthreads();

    // ---- stage 1: each thread owns 4 hidden columns (j = jj*256+tid), all 16 tokens ----
    const float* W1e = W1 + (size_t)e * D_ * H_;
    float acc[4][TM];
#pragma unroll
    for (int jj = 0; jj < 4; ++jj)
#pragma unroll
        for (int m = 0; m < TM; ++m) acc[jj][m] = 0.f;

    for (int d4 = 0; d4 < D_ / 4; ++d4) {
        float w[4][4];
#pragma unroll
        for (int dd = 0; dd < 4; ++dd) {
            const float* wp = W1e + (size_t)(d4 * 4 + dd) * H_ + tid;
#pragma unroll
            for (int jj = 0; jj < 4; ++jj) w[dd][jj] = wp[jj * 256];
        }
#pragma unroll
        for (int m = 0; m < TM; ++m) {
            const float4 xv = ((const float4*)&Xs[m][0])[d4];  // broadcast LDS read
            const float* xp = &xv.x;
#pragma unroll
            for (int dd = 0; dd < 4; ++dd)
#pragma unroll
                for (int jj = 0; jj < 4; ++jj)
                    acc[jj][m] = fmaf(xp[dd], w[dd][jj], acc[jj][m]);
        }
    }
#pragma unroll
    for (int jj = 0; jj < 4; ++jj) {
        const int j = jj * 256 + tid;
        const float bv = b1[e * H_ + j];
#pragma unroll
        for (int m = 0; m < TM; ++m) Hs[m][j] = fmaxf(acc[jj][m] + bv, 0.f);
    }
    __syncthreads();

    // ---- stage 2: each thread owns 2 output columns (o = oo*256+tid), all 16 tokens ----
    const float* W2e = W2 + (size_t)e * H_ * D_;
    float acc2[2][TM];
#pragma unroll
    for (int oo = 0; oo < 2; ++oo)
#pragma unroll
        for (int m = 0; m < TM; ++m) acc2[oo][m] = 0.f;

    for (int j4 = 0; j4 < H_ / 4; ++j4) {
        float w[4][2];
#pragma unroll
        for (int dd = 0; dd < 4; ++dd) {
            const float* wp = W2e + (size_t)(j4 * 4 + dd) * D_ + tid;
#pragma unroll
            for (int oo = 0; oo < 2; ++oo) w[dd][oo] = wp[oo * 256];
        }
#pragma unroll
        for (int m = 0; m < TM; ++m) {
            const float4 hv = ((const float4*)&Hs[m][0])[j4];  // broadcast LDS read
            const float* hp = &hv.x;
#pragma unroll
            for (int dd = 0; dd < 4; ++dd)
#pragma unroll
                for (int oo = 0; oo < 2; ++oo)
                    acc2[oo][m] = fmaf(hp[dd], w[dd][oo], acc2[oo][m]);
        }
    }
#pragma unroll
    for (int oo = 0; oo < 2; ++oo) {
        const int o = oo * 256 + tid;
        const float bv = b2[e * D_ + o];
        for (int m = 0; m < mact; ++m) {
            atomicAdd(out + (size_t)tks[m] * D_ + o, (acc2[oo][m] + bv) * gs[m]);
        }
    }
}

extern "C" void kernel_launch(void* const* d_in, const int* in_sizes, int n_in,
                              void* d_out, int out_size, void* d_ws, size_t ws_size,
                              hipStream_t stream)
{
    const float* x    = (const float*)d_in[0];
    const int*   mask = (const int*)d_in[1];
    const float* wg   = (const float*)d_in[2];
    const float* W1   = (const float*)d_in[3];
    const float* b1   = (const float*)d_in[4];
    const float* W2   = (const float*)d_in[5];
    const float* b2   = (const float*)d_in[6];
    float* out = (float*)d_out;

    char* ws = (char*)d_ws;
    int*   counts = (int*)ws;                              // 8 ints (pad to 256B)
    int*   lists  = (int*)(ws + 256);                      // E*NT ints
    float* gvals  = (float*)(ws + 256 + E_ * NT_ * 4);     // E*NT floats

    hipMemsetAsync(counts, 0, E_ * sizeof(int), stream);
    gating_kernel<<<NT_ / 4, 256, 0, stream>>>(x, mask, wg, counts, lists, gvals);
    init_out_kernel<<<(NT_ * D_) / 4 / 256, 256, 0, stream>>>(x, out);
    expert_kernel<<<dim3(NT_ / TM, E_), 256, 0, stream>>>(x, W1, b1, W2, b2,
                                                          counts, lists, gvals, out);
}

// Round 2
// 205.173 us; speedup vs baseline: 2.0911x; 2.0911x over previous
//
#include <hip/hip_runtime.h>
#include <cmath>

#define B_ 8
#define S_ 512
#define D_ 512
#define H_ 1024
#define E_ 8
#define NT_ (B_*S_)   // 4096 tokens
#define TM 16         // tokens per expert tile

typedef __attribute__((ext_vector_type(8))) short short8v;
typedef __attribute__((ext_vector_type(4))) float f32x4;

__device__ inline unsigned short f2bf(float f) {
    union { float f; unsigned u; } a; a.f = f;
    unsigned u = a.u;
    return (unsigned short)((u + 0x7FFF + ((u >> 16) & 1)) >> 16);  // RNE
}

// ---------------- gating: one wave (64 lanes) per token ----------------
__global__ __launch_bounds__(256) void gating_kernel(
    const float* __restrict__ x, const int* __restrict__ mask,
    const float* __restrict__ wg, int* __restrict__ counts,
    int* __restrict__ lists, float* __restrict__ gvals)
{
    const int wave = threadIdx.x >> 6;
    const int lane = threadIdx.x & 63;
    const int t = blockIdx.x * 4 + wave;
    const float* xr = x + (size_t)t * D_;
    float acc[E_];
#pragma unroll
    for (int e = 0; e < E_; ++e) acc[e] = 0.f;
    for (int d = lane; d < D_; d += 64) {
        const float xv = xr[d];
        const float* wr = wg + (size_t)d * E_;
#pragma unroll
        for (int e = 0; e < E_; ++e) acc[e] += xv * wr[e];
    }
#pragma unroll
    for (int e = 0; e < E_; ++e) {
        float v = acc[e];
#pragma unroll
        for (int off = 32; off > 0; off >>= 1) v += __shfl_down(v, off, 64);
        acc[e] = v;
    }
    if (lane == 0 && mask[t] != 0) {
        int i0 = 0; float v0 = acc[0];
#pragma unroll
        for (int e = 1; e < E_; ++e) if (acc[e] > v0) { v0 = acc[e]; i0 = e; }
        int i1 = -1; float v1 = -INFINITY;
#pragma unroll
        for (int e = 0; e < E_; ++e) if (e != i0 && acc[e] > v1) { v1 = acc[e]; i1 = e; }
        const float ex = __expf(v1 - v0);
        const float denom = 1.f + ex;
        const int p0 = atomicAdd(&counts[i0], 1);
        lists[i0 * NT_ + p0] = t; gvals[i0 * NT_ + p0] = 1.f / denom;
        const int p1 = atomicAdd(&counts[i1], 1);
        lists[i1 * NT_ + p1] = t; gvals[i1 * NT_ + p1] = ex / denom;
    }
}

// ---------------- residual init: out = x ----------------
__global__ __launch_bounds__(256) void init_out_kernel(
    const float* __restrict__ x, float* __restrict__ out)
{
    const size_t i = (size_t)blockIdx.x * blockDim.x + threadIdx.x;
    ((float4*)out)[i] = ((const float4*)x)[i];
}

// ---------------- transpose + fp32->bf16: dst[c][r] = src[r][c] ----------------
__global__ __launch_bounds__(256) void transpose_cvt(
    const float* __restrict__ src, unsigned short* __restrict__ dst, int R, int C)
{
    __shared__ unsigned short t[64][72];
    const float* s = src + (size_t)blockIdx.z * R * C;
    unsigned short* d = dst + (size_t)blockIdx.z * R * C;
    const int r0 = blockIdx.y * 64, c0 = blockIdx.x * 64;
    const int tc = threadIdx.x & 63;
    const int tr = threadIdx.x >> 6;
#pragma unroll
    for (int i = 0; i < 16; ++i) {
        const int r = tr + i * 4;
        t[r][tc] = f2bf(s[(size_t)(r0 + r) * C + c0 + tc]);
    }
    __syncthreads();
    const int c = threadIdx.x >> 2;        // 0..63 : row of dst tile
    const int ch = threadIdx.x & 3;        // 16-elem chunk
#pragma unroll
    for (int half = 0; half < 2; ++half) {
        union { unsigned short u[8]; uint4 v; } p;
#pragma unroll
        for (int k = 0; k < 8; ++k) p.u[k] = t[ch * 16 + half * 8 + k][c];
        *(uint4*)(d + (size_t)(c0 + c) * R + r0 + ch * 16 + half * 8) = p.v;
    }
}

// ---------------- fused 2-stage expert MLP, MFMA bf16 ----------------
// blockIdx.x: bi; expert e = bi&7 (XCD-pinned), tile = bi>>3, 16 tokens/tile.
// Stage1: Hs[16][1024] = relu(Xs[16][512] @ W1T^T + b1);  Stage2: out += gate*(Hs @ W2T^T + b2)
__global__ __launch_bounds__(256) void expert_mfma(
    const float* __restrict__ x,
    const unsigned short* __restrict__ W1T,   // [E][H][D] bf16
    const float* __restrict__ b1,
    const unsigned short* __restrict__ W2T,   // [E][D][H] bf16
    const float* __restrict__ b2,
    const int* __restrict__ counts, const int* __restrict__ lists,
    const float* __restrict__ gvals, float* __restrict__ out)
{
    __shared__ unsigned short Xs[TM * D_];    // 16 KB, swizzled
    __shared__ unsigned short Hs[TM * H_];    // 32 KB, swizzled
    __shared__ int   tks[TM];
    __shared__ float gs[TM];

    const int bi = blockIdx.x;
    const int e = bi & 7;
    const int t0 = (bi >> 3) * TM;
    const int n = counts[e];
    if (t0 >= n) return;
    const int tid = threadIdx.x;
    const int mact = min(TM, n - t0);
    const int wave = tid >> 6;
    const int lane = tid & 63;
    const int m = lane & 15;      // A-row / B-col within fragment
    const int g = lane >> 4;      // k-group
    char* XsC = (char*)Xs;
    char* HsC = (char*)Hs;

    if (tid < TM) {
        if (tid < mact) {
            tks[tid] = lists[e * NT_ + t0 + tid];
            gs[tid]  = gvals[e * NT_ + t0 + tid];
        } else { tks[tid] = 0; gs[tid] = 0.f; }
    }
    __syncthreads();

    // stage X tile -> LDS bf16 (swizzled); 1024 16B-chunks, 4 per thread
    for (int idx = tid; idx < TM * (D_ / 8); idx += 256) {
        const int mm = idx >> 6;        // row
        const int c8 = idx & 63;        // 8-elem chunk in row
        union { unsigned short u[8]; uint4 v; } p;
        if (mm < mact) {
            const float4* xr = (const float4*)(x + (size_t)tks[mm] * D_);
            const float4 v0 = xr[c8 * 2], v1 = xr[c8 * 2 + 1];
            p.u[0]=f2bf(v0.x); p.u[1]=f2bf(v0.y); p.u[2]=f2bf(v0.z); p.u[3]=f2bf(v0.w);
            p.u[4]=f2bf(v1.x); p.u[5]=f2bf(v1.y); p.u[6]=f2bf(v1.z); p.u[7]=f2bf(v1.w);
        } else {
            p.v = make_uint4(0, 0, 0, 0);
        }
        const int off = mm * (D_ * 2) + c8 * 16;
        *(uint4*)(XsC + (off ^ ((mm & 7) << 4))) = p.v;
    }
    __syncthreads();

    // ---- stage 1: wave owns 256 h-cols (16 frags); K = 512 ----
    const int nbase = wave * 256;
    f32x4 acc1[16];
#pragma unroll
    for (int f = 0; f < 16; ++f) acc1[f] = (f32x4){0.f, 0.f, 0.f, 0.f};

    for (int k0 = 0; k0 < D_; k0 += 32) {
        const int aoff = m * (D_ * 2) + k0 * 2 + g * 16;
        const short8v a = *(const short8v*)(XsC + (aoff ^ ((m & 7) << 4)));
#pragma unroll
        for (int f = 0; f < 16; ++f) {
            const unsigned short* bp = W1T + (((size_t)(e << 10) + nbase + f * 16 + m) << 9) + k0 + g * 8;
            const short8v b = *(const short8v*)bp;
            acc1[f] = __builtin_amdgcn_mfma_f32_16x16x32_bf16(a, b, acc1[f], 0, 0, 0);
        }
    }
#pragma unroll
    for (int f = 0; f < 16; ++f) {
        const int nn = nbase + f * 16 + m;
        const float bias = b1[(e << 10) + nn];
#pragma unroll
        for (int r = 0; r < 4; ++r) {
            const int mm = g * 4 + r;
            const unsigned short hv = f2bf(fmaxf(acc1[f][r] + bias, 0.f));
            const int off = mm * (H_ * 2) + nn * 2;
            *(unsigned short*)(HsC + (off ^ ((mm & 7) << 4))) = hv;
        }
    }
    __syncthreads();

    // ---- stage 2: wave owns 128 o-cols (8 frags); K = 1024 ----
    const int obase = wave * 128;
    f32x4 acc2[8];
#pragma unroll
    for (int f = 0; f < 8; ++f) acc2[f] = (f32x4){0.f, 0.f, 0.f, 0.f};

    for (int k0 = 0; k0 < H_; k0 += 32) {
        const int aoff = m * (H_ * 2) + k0 * 2 + g * 16;
        const short8v a = *(const short8v*)(HsC + (aoff ^ ((m & 7) << 4)));
#pragma unroll
        for (int f = 0; f < 8; ++f) {
            const unsigned short* bp = W2T + (((size_t)(e << 9) + obase + f * 16 + m) << 10) + k0 + g * 8;
            const short8v b = *(const short8v*)bp;
            acc2[f] = __builtin_amdgcn_mfma_f32_16x16x32_bf16(a, b, acc2[f], 0, 0, 0);
        }
    }
#pragma unroll
    for (int f = 0; f < 8; ++f) {
        const int o = obase + f * 16 + m;
        const float bias = b2[(e << 9) + o];
#pragma unroll
        for (int r = 0; r < 4; ++r) {
            const int mm = g * 4 + r;
            const float gv = gs[mm];
            if (gv != 0.f)
                atomicAdd(out + (size_t)tks[mm] * D_ + o, (acc2[f][r] + bias) * gv);
        }
    }
}

// ---------------- fallback fp32 expert kernel (round-1, used if ws too small) ----------------
__global__ __launch_bounds__(256) void expert_fp32(
    const float* __restrict__ x,
    const float* __restrict__ W1, const float* __restrict__ b1,
    const float* __restrict__ W2, const float* __restrict__ b2,
    const int* __restrict__ counts, const int* __restrict__ lists,
    const float* __restrict__ gvals, float* __restrict__ out)
{
    __shared__ float Xs[TM][D_];
    __shared__ float Hs[TM][H_];
    __shared__ int   tks[TM];
    __shared__ float gs[TM];

    const int e  = blockIdx.y;
    const int n  = counts[e];
    const int t0 = blockIdx.x * TM;
    if (t0 >= n) return;
    const int tid  = threadIdx.x;
    const int mact = min(TM, n - t0);

    if (tid < TM) {
        if (tid < mact) {
            tks[tid] = lists[e * NT_ + t0 + tid];
            gs[tid]  = gvals[e * NT_ + t0 + tid];
        } else { tks[tid] = 0; gs[tid] = 0.f; }
    }
    __syncthreads();
    for (int idx = tid; idx < TM * (D_ / 4); idx += 256) {
        const int mm = idx >> 7, c = idx & 127;
        float4 v = make_float4(0.f, 0.f, 0.f, 0.f);
        if (mm < mact) v = ((const float4*)(x + (size_t)tks[mm] * D_))[c];
        ((float4*)&Xs[mm][0])[c] = v;
    }
    __syncthreads();
    const float* W1e = W1 + (size_t)e * D_ * H_;
    float acc[4][TM];
#pragma unroll
    for (int jj = 0; jj < 4; ++jj)
#pragma unroll
        for (int mm = 0; mm < TM; ++mm) acc[jj][mm] = 0.f;
    for (int d4 = 0; d4 < D_ / 4; ++d4) {
        float w[4][4];
#pragma unroll
        for (int dd = 0; dd < 4; ++dd) {
            const float* wp = W1e + (size_t)(d4 * 4 + dd) * H_ + tid;
#pragma unroll
            for (int jj = 0; jj < 4; ++jj) w[dd][jj] = wp[jj * 256];
        }
#pragma unroll
        for (int mm = 0; mm < TM; ++mm) {
            const float4 xv = ((const float4*)&Xs[mm][0])[d4];
            const float* xp = &xv.x;
#pragma unroll
            for (int dd = 0; dd < 4; ++dd)
#pragma unroll
                for (int jj = 0; jj < 4; ++jj)
                    acc[jj][mm] = fmaf(xp[dd], w[dd][jj], acc[jj][mm]);
        }
    }
#pragma unroll
    for (int jj = 0; jj < 4; ++jj) {
        const int j = jj * 256 + tid;
        const float bv = b1[e * H_ + j];
#pragma unroll
        for (int mm = 0; mm < TM; ++mm) Hs[mm][j] = fmaxf(acc[jj][mm] + bv, 0.f);
    }
    __syncthreads();
    const float* W2e = W2 + (size_t)e * H_ * D_;
    float acc2[2][TM];
#pragma unroll
    for (int oo = 0; oo < 2; ++oo)
#pragma unroll
        for (int mm = 0; mm < TM; ++mm) acc2[oo][mm] = 0.f;
    for (int j4 = 0; j4 < H_ / 4; ++j4) {
        float w[4][2];
#pragma unroll
        for (int dd = 0; dd < 4; ++dd) {
            const float* wp = W2e + (size_t)(j4 * 4 + dd) * D_ + tid;
#pragma unroll
            for (int oo = 0; oo < 2; ++oo) w[dd][oo] = wp[oo * 256];
        }
#pragma unroll
        for (int mm = 0; mm < TM; ++mm) {
            const float4 hv = ((const float4*)&Hs[mm][0])[j4];
            const float* hp = &hv.x;
#pragma unroll
            for (int dd = 0; dd < 4; ++dd)
#pragma unroll
                for (int oo = 0; oo < 2; ++oo)
                    acc2[oo][mm] = fmaf(hp[dd], w[dd][oo], acc2[oo][mm]);
        }
    }
#pragma unroll
    for (int oo = 0; oo < 2; ++oo) {
        const int o = oo * 256 + tid;
        const float bv = b2[e * D_ + o];
        for (int mm = 0; mm < mact; ++mm)
            atomicAdd(out + (size_t)tks[mm] * D_ + o, (acc2[oo][mm] + bv) * gs[mm]);
    }
}

extern "C" void kernel_launch(void* const* d_in, const int* in_sizes, int n_in,
                              void* d_out, int out_size, void* d_ws, size_t ws_size,
                              hipStream_t stream)
{
    const float* x    = (const float*)d_in[0];
    const int*   mask = (const int*)d_in[1];
    const float* wg   = (const float*)d_in[2];
    const float* W1   = (const float*)d_in[3];
    const float* b1   = (const float*)d_in[4];
    const float* W2   = (const float*)d_in[5];
    const float* b2   = (const float*)d_in[6];
    float* out = (float*)d_out;

    char* ws = (char*)d_ws;
    int*   counts = (int*)ws;
    int*   lists  = (int*)(ws + 256);
    float* gvals  = (float*)(ws + 256 + E_ * NT_ * 4);

    const size_t wt_bytes = (size_t)E_ * D_ * H_ * 2;      // 8 MB each
    const size_t need = 524288 + 2 * wt_bytes;             // ~17.3 MB

    hipMemsetAsync(counts, 0, E_ * sizeof(int), stream);
    gating_kernel<<<NT_ / 4, 256, 0, stream>>>(x, mask, wg, counts, lists, gvals);
    init_out_kernel<<<(NT_ * D_) / 4 / 256, 256, 0, stream>>>(x, out);

    if (ws_size >= need) {
        unsigned short* W1T = (unsigned short*)(ws + 524288);
        unsigned short* W2T = (unsigned short*)(ws + 524288 + wt_bytes);
        transpose_cvt<<<dim3(H_ / 64, D_ / 64, E_), 256, 0, stream>>>(W1, W1T, D_, H_);
        transpose_cvt<<<dim3(D_ / 64, H_ / 64, E_), 256, 0, stream>>>(W2, W2T, H_, D_);
        expert_mfma<<<(NT_ / TM) * E_, 256, 0, stream>>>(x, W1T, b1, W2T, b2,
                                                         counts, lists, gvals, out);
    } else {
        expert_fp32<<<dim3(NT_ / TM, E_), 256, 0, stream>>>(x, W1, b1, W2, b2,
                                                            counts, lists, gvals, out);
    }
}

// Round 3
// 162.657 us; speedup vs baseline: 2.6377x; 1.2614x over previous
//
#include <hip/hip_runtime.h>
#include <cmath>

#define B_ 8
#define S_ 512
#define D_ 512
#define H_ 1024
#define E_ 8
#define NT_ (B_*S_)   // 4096 tokens
#define TM 16         // tokens per tile (round-2 fallback path)

typedef __attribute__((ext_vector_type(8))) short short8v;
typedef __attribute__((ext_vector_type(4))) float f32x4;

__device__ inline unsigned short f2bf(float f) {
    union { float f; unsigned u; } a; a.f = f;
    unsigned u = a.u;
    return (unsigned short)((u + 0x7FFF + ((u >> 16) & 1)) >> 16);  // RNE
}

// ======================= TIER A (main path) =======================

// ---- prep0: out = x (residual), xbf = bf16(x), zero counts ----
__global__ __launch_bounds__(256) void prep0_kernel(
    const float* __restrict__ x, float* __restrict__ out,
    unsigned short* __restrict__ xbf, int* __restrict__ counts)
{
    if (blockIdx.x == 0 && threadIdx.x < E_) counts[threadIdx.x] = 0;
    const size_t i = (size_t)blockIdx.x * 256 + threadIdx.x;   // one per 8 floats
    const float4 v0 = ((const float4*)x)[i * 2];
    const float4 v1 = ((const float4*)x)[i * 2 + 1];
    ((float4*)out)[i * 2]     = v0;
    ((float4*)out)[i * 2 + 1] = v1;
    union { unsigned short u[8]; uint4 v; } p;
    p.u[0]=f2bf(v0.x); p.u[1]=f2bf(v0.y); p.u[2]=f2bf(v0.z); p.u[3]=f2bf(v0.w);
    p.u[4]=f2bf(v1.x); p.u[5]=f2bf(v1.y); p.u[6]=f2bf(v1.z); p.u[7]=f2bf(v1.w);
    ((uint4*)xbf)[i] = p.v;
}

// ---- prep1: blocks 0..1023 gating; 1024..2047 W1 transpose; 2048..3071 W2 transpose ----
__global__ __launch_bounds__(256) void prep1_kernel(
    const float* __restrict__ x, const int* __restrict__ mask,
    const float* __restrict__ wg,
    const float* __restrict__ W1, const float* __restrict__ W2,
    int* __restrict__ counts, int* __restrict__ lists, float* __restrict__ gvals,
    unsigned short* __restrict__ W1T, unsigned short* __restrict__ W2T)
{
    const int bid = blockIdx.x;
    const int tid = threadIdx.x;
    if (bid < 1024) {
        // -------- gating: one wave per token --------
        const int wave = tid >> 6, lane = tid & 63;
        const int t = bid * 4 + wave;
        const float* xr = x + (size_t)t * D_;
        float acc[E_];
#pragma unroll
        for (int e = 0; e < E_; ++e) acc[e] = 0.f;
        for (int d = lane; d < D_; d += 64) {
            const float xv = xr[d];
            const float* wr = wg + (size_t)d * E_;
#pragma unroll
            for (int e = 0; e < E_; ++e) acc[e] += xv * wr[e];
        }
#pragma unroll
        for (int e = 0; e < E_; ++e) {
            float v = acc[e];
#pragma unroll
            for (int off = 32; off > 0; off >>= 1) v += __shfl_down(v, off, 64);
            acc[e] = v;
        }
        if (lane == 0 && mask[t] != 0) {
            int i0 = 0; float v0 = acc[0];
#pragma unroll
            for (int e = 1; e < E_; ++e) if (acc[e] > v0) { v0 = acc[e]; i0 = e; }
            int i1 = -1; float v1 = -INFINITY;
#pragma unroll
            for (int e = 0; e < E_; ++e) if (e != i0 && acc[e] > v1) { v1 = acc[e]; i1 = e; }
            const float ex = __expf(v1 - v0);
            const float denom = 1.f + ex;
            const int p0 = atomicAdd(&counts[i0], 1);
            lists[i0 * NT_ + p0] = t; gvals[i0 * NT_ + p0] = 1.f / denom;
            const int p1 = atomicAdd(&counts[i1], 1);
            lists[i1 * NT_ + p1] = t; gvals[i1 * NT_ + p1] = ex / denom;
        }
    } else {
        // -------- 64x64 transpose+cvt tile --------
        __shared__ unsigned short tT[64][72];
        const float* s; unsigned short* d; int R, C, r0, c0;
        if (bid < 2048) {
            const int t = bid - 1024; const int e = t >> 7; const int rem = t & 127;
            R = D_; C = H_; c0 = (rem & 15) * 64; r0 = (rem >> 4) * 64;
            s = W1 + (size_t)e * R * C; d = W1T + (size_t)e * R * C;
        } else {
            const int t = bid - 2048; const int e = t >> 7; const int rem = t & 127;
            R = H_; C = D_; c0 = (rem & 7) * 64; r0 = (rem >> 3) * 64;
            s = W2 + (size_t)e * R * C; d = W2T + (size_t)e * R * C;
        }
        const int c4 = tid & 15, rr = tid >> 4;
#pragma unroll
        for (int pass = 0; pass < 4; ++pass) {
            const int r = rr + pass * 16;
            const float4 v = *(const float4*)(s + (size_t)(r0 + r) * C + c0 + c4 * 4);
            tT[r][c4 * 4 + 0] = f2bf(v.x);
            tT[r][c4 * 4 + 1] = f2bf(v.y);
            tT[r][c4 * 4 + 2] = f2bf(v.z);
            tT[r][c4 * 4 + 3] = f2bf(v.w);
        }
        __syncthreads();
        const int c = tid >> 2, ch = tid & 3;
#pragma unroll
        for (int half = 0; half < 2; ++half) {
            union { unsigned short u[8]; uint4 v; } p;
#pragma unroll
            for (int k = 0; k < 8; ++k) p.u[k] = tT[ch * 16 + half * 8 + k][c];
            *(uint4*)(d + (size_t)(c0 + c) * R + r0 + ch * 16 + half * 8) = p.v;
        }
    }
}

// ---- per-block (expert, tile) mapping from counts prefix ----
__device__ inline bool find_tile(const int* __restrict__ counts, int tflat,
                                 int& e, int& t0, int& off, int& n_e)
{
    int cum = 0, offacc = 0; e = -1;
#pragma unroll
    for (int i = 0; i < E_; ++i) {
        const int c = counts[i];
        const int t = (c + 31) >> 5;
        if (e < 0 && tflat < cum + t) { e = i; t0 = (tflat - cum) << 5; off = offacc; n_e = c; }
        cum += t; offacc += c;
    }
    return e >= 0;
}

// ---- stage1: H[slot][h] = relu(Xbf[tok] @ W1T^T + b1), streaming MFMA ----
// grid.x = 264*4;  block tile = 32 tokens x 256 cols; wave tile = 32x64
__global__ __launch_bounds__(256) void stage1_kernel(
    const unsigned short* __restrict__ xbf,
    const unsigned short* __restrict__ W1T, const float* __restrict__ b1,
    const int* __restrict__ counts, const int* __restrict__ lists,
    unsigned short* __restrict__ Hbuf)
{
    const int nb = blockIdx.x & 3;
    const int tflat = blockIdx.x >> 2;
    int e, t0, off, n_e;
    if (!find_tile(counts, tflat, e, t0, off, n_e)) return;
    const int mact = min(32, n_e - t0);
    __shared__ int tks[32];
    const int tid = threadIdx.x;
    if (tid < 32) tks[tid] = lists[e * NT_ + t0 + min(tid, mact - 1)];
    __syncthreads();

    const int wave = tid >> 6, lane = tid & 63, m = lane & 15, g = lane >> 4;
    const int colbase = nb * 256 + wave * 64;

    const unsigned short* a0p = xbf + ((size_t)tks[m] << 9) + g * 8;
    const unsigned short* a1p = xbf + ((size_t)tks[16 + m] << 9) + g * 8;
    const unsigned short* bp0 = W1T + (((size_t)(e << 10) + colbase +  0 + m) << 9) + g * 8;
    const unsigned short* bp1 = W1T + (((size_t)(e << 10) + colbase + 16 + m) << 9) + g * 8;
    const unsigned short* bp2 = W1T + (((size_t)(e << 10) + colbase + 32 + m) << 9) + g * 8;
    const unsigned short* bp3 = W1T + (((size_t)(e << 10) + colbase + 48 + m) << 9) + g * 8;

    f32x4 acc[2][4];
#pragma unroll
    for (int i = 0; i < 2; ++i)
#pragma unroll
        for (int f = 0; f < 4; ++f) acc[i][f] = (f32x4){0.f, 0.f, 0.f, 0.f};

#pragma unroll 2
    for (int k0 = 0; k0 < D_; k0 += 32) {
        const short8v a0 = *(const short8v*)(a0p + k0);
        const short8v a1 = *(const short8v*)(a1p + k0);
        const short8v b0 = *(const short8v*)(bp0 + k0);
        const short8v b1v = *(const short8v*)(bp1 + k0);
        const short8v b2v = *(const short8v*)(bp2 + k0);
        const short8v b3 = *(const short8v*)(bp3 + k0);
        acc[0][0] = __builtin_amdgcn_mfma_f32_16x16x32_bf16(a0, b0,  acc[0][0], 0, 0, 0);
        acc[1][0] = __builtin_amdgcn_mfma_f32_16x16x32_bf16(a1, b0,  acc[1][0], 0, 0, 0);
        acc[0][1] = __builtin_amdgcn_mfma_f32_16x16x32_bf16(a0, b1v, acc[0][1], 0, 0, 0);
        acc[1][1] = __builtin_amdgcn_mfma_f32_16x16x32_bf16(a1, b1v, acc[1][1], 0, 0, 0);
        acc[0][2] = __builtin_amdgcn_mfma_f32_16x16x32_bf16(a0, b2v, acc[0][2], 0, 0, 0);
        acc[1][2] = __builtin_amdgcn_mfma_f32_16x16x32_bf16(a1, b2v, acc[1][2], 0, 0, 0);
        acc[0][3] = __builtin_amdgcn_mfma_f32_16x16x32_bf16(a0, b3,  acc[0][3], 0, 0, 0);
        acc[1][3] = __builtin_amdgcn_mfma_f32_16x16x32_bf16(a1, b3,  acc[1][3], 0, 0, 0);
    }

#pragma unroll
    for (int f = 0; f < 4; ++f) {
        const int col = colbase + f * 16 + m;
        const float bias = b1[(e << 10) + col];
#pragma unroll
        for (int i = 0; i < 2; ++i)
#pragma unroll
            for (int r = 0; r < 4; ++r) {
                const int row = i * 16 + g * 4 + r;
                if (row < mact)
                    Hbuf[((size_t)(off + t0 + row) << 10) + col] =
                        f2bf(fmaxf(acc[i][f][r] + bias, 0.f));
            }
    }
}

// ---- stage2: out[tok] += gate * (H[slot] @ W2T^T + b2), streaming MFMA ----
// grid.x = 264*2;  block tile = 32 rows x 256 cols; wave tile = 32x64
__global__ __launch_bounds__(256) void stage2_kernel(
    const unsigned short* __restrict__ Hbuf,
    const unsigned short* __restrict__ W2T, const float* __restrict__ b2,
    const int* __restrict__ counts, const int* __restrict__ lists,
    const float* __restrict__ gvals, float* __restrict__ out)
{
    const int nb = blockIdx.x & 1;
    const int tflat = blockIdx.x >> 1;
    int e, t0, off, n_e;
    if (!find_tile(counts, tflat, e, t0, off, n_e)) return;
    const int mact = min(32, n_e - t0);
    __shared__ int tks[32];
    __shared__ float gsh[32];
    const int tid = threadIdx.x;
    if (tid < 32) {
        const int idx = min(tid, mact - 1);
        tks[tid] = lists[e * NT_ + t0 + idx];
        gsh[tid] = gvals[e * NT_ + t0 + idx];
    }
    __syncthreads();

    const int wave = tid >> 6, lane = tid & 63, m = lane & 15, g = lane >> 4;
    const int colbase = nb * 256 + wave * 64;

    const unsigned short* a0p = Hbuf + ((size_t)(off + t0 + m) << 10) + g * 8;
    const unsigned short* a1p = Hbuf + ((size_t)(off + t0 + 16 + m) << 10) + g * 8;
    const unsigned short* bp0 = W2T + (((size_t)(e << 9) + colbase +  0 + m) << 10) + g * 8;
    const unsigned short* bp1 = W2T + (((size_t)(e << 9) + colbase + 16 + m) << 10) + g * 8;
    const unsigned short* bp2 = W2T + (((size_t)(e << 9) + colbase + 32 + m) << 10) + g * 8;
    const unsigned short* bp3 = W2T + (((size_t)(e << 9) + colbase + 48 + m) << 10) + g * 8;

    f32x4 acc[2][4];
#pragma unroll
    for (int i = 0; i < 2; ++i)
#pragma unroll
        for (int f = 0; f < 4; ++f) acc[i][f] = (f32x4){0.f, 0.f, 0.f, 0.f};

#pragma unroll 2
    for (int k0 = 0; k0 < H_; k0 += 32) {
        const short8v a0 = *(const short8v*)(a0p + k0);
        const short8v a1 = *(const short8v*)(a1p + k0);
        const short8v b0 = *(const short8v*)(bp0 + k0);
        const short8v b1v = *(const short8v*)(bp1 + k0);
        const short8v b2v = *(const short8v*)(bp2 + k0);
        const short8v b3 = *(const short8v*)(bp3 + k0);
        acc[0][0] = __builtin_amdgcn_mfma_f32_16x16x32_bf16(a0, b0,  acc[0][0], 0, 0, 0);
        acc[1][0] = __builtin_amdgcn_mfma_f32_16x16x32_bf16(a1, b0,  acc[1][0], 0, 0, 0);
        acc[0][1] = __builtin_amdgcn_mfma_f32_16x16x32_bf16(a0, b1v, acc[0][1], 0, 0, 0);
        acc[1][1] = __builtin_amdgcn_mfma_f32_16x16x32_bf16(a1, b1v, acc[1][1], 0, 0, 0);
        acc[0][2] = __builtin_amdgcn_mfma_f32_16x16x32_bf16(a0, b2v, acc[0][2], 0, 0, 0);
        acc[1][2] = __builtin_amdgcn_mfma_f32_16x16x32_bf16(a1, b2v, acc[1][2], 0, 0, 0);
        acc[0][3] = __builtin_amdgcn_mfma_f32_16x16x32_bf16(a0, b3,  acc[0][3], 0, 0, 0);
        acc[1][3] = __builtin_amdgcn_mfma_f32_16x16x32_bf16(a1, b3,  acc[1][3], 0, 0, 0);
    }

#pragma unroll
    for (int f = 0; f < 4; ++f) {
        const int col = colbase + f * 16 + m;
        const float bias = b2[(e << 9) + col];
#pragma unroll
        for (int i = 0; i < 2; ++i)
#pragma unroll
            for (int r = 0; r < 4; ++r) {
                const int row = i * 16 + g * 4 + r;
                if (row < mact)
                    atomicAdd(out + ((size_t)tks[row] << 9) + col,
                              (acc[i][f][r] + bias) * gsh[row]);
            }
    }
}

// ======================= TIER B/C fallbacks (round-1/2 paths) =======================

__global__ __launch_bounds__(256) void gating_kernel(
    const float* __restrict__ x, const int* __restrict__ mask,
    const float* __restrict__ wg, int* __restrict__ counts,
    int* __restrict__ lists, float* __restrict__ gvals)
{
    const int wave = threadIdx.x >> 6;
    const int lane = threadIdx.x & 63;
    const int t = blockIdx.x * 4 + wave;
    const float* xr = x + (size_t)t * D_;
    float acc[E_];
#pragma unroll
    for (int e = 0; e < E_; ++e) acc[e] = 0.f;
    for (int d = lane; d < D_; d += 64) {
        const float xv = xr[d];
        const float* wr = wg + (size_t)d * E_;
#pragma unroll
        for (int e = 0; e < E_; ++e) acc[e] += xv * wr[e];
    }
#pragma unroll
    for (int e = 0; e < E_; ++e) {
        float v = acc[e];
#pragma unroll
        for (int off = 32; off > 0; off >>= 1) v += __shfl_down(v, off, 64);
        acc[e] = v;
    }
    if (lane == 0 && mask[t] != 0) {
        int i0 = 0; float v0 = acc[0];
#pragma unroll
        for (int e = 1; e < E_; ++e) if (acc[e] > v0) { v0 = acc[e]; i0 = e; }
        int i1 = -1; float v1 = -INFINITY;
#pragma unroll
        for (int e = 0; e < E_; ++e) if (e != i0 && acc[e] > v1) { v1 = acc[e]; i1 = e; }
        const float ex = __expf(v1 - v0);
        const float denom = 1.f + ex;
        const int p0 = atomicAdd(&counts[i0], 1);
        lists[i0 * NT_ + p0] = t; gvals[i0 * NT_ + p0] = 1.f / denom;
        const int p1 = atomicAdd(&counts[i1], 1);
        lists[i1 * NT_ + p1] = t; gvals[i1 * NT_ + p1] = ex / denom;
    }
}

__global__ __launch_bounds__(256) void init_out_kernel(
    const float* __restrict__ x, float* __restrict__ out)
{
    const size_t i = (size_t)blockIdx.x * blockDim.x + threadIdx.x;
    ((float4*)out)[i] = ((const float4*)x)[i];
}

__global__ __launch_bounds__(256) void transpose_cvt(
    const float* __restrict__ src, unsigned short* __restrict__ dst, int R, int C)
{
    __shared__ unsigned short t[64][72];
    const float* s = src + (size_t)blockIdx.z * R * C;
    unsigned short* d = dst + (size_t)blockIdx.z * R * C;
    const int r0 = blockIdx.y * 64, c0 = blockIdx.x * 64;
    const int tc = threadIdx.x & 63;
    const int tr = threadIdx.x >> 6;
#pragma unroll
    for (int i = 0; i < 16; ++i) {
        const int r = tr + i * 4;
        t[r][tc] = f2bf(s[(size_t)(r0 + r) * C + c0 + tc]);
    }
    __syncthreads();
    const int c = threadIdx.x >> 2;
    const int ch = threadIdx.x & 3;
#pragma unroll
    for (int half = 0; half < 2; ++half) {
        union { unsigned short u[8]; uint4 v; } p;
#pragma unroll
        for (int k = 0; k < 8; ++k) p.u[k] = t[ch * 16 + half * 8 + k][c];
        *(uint4*)(d + (size_t)(c0 + c) * R + r0 + ch * 16 + half * 8) = p.v;
    }
}

__global__ __launch_bounds__(256) void expert_mfma(
    const float* __restrict__ x,
    const unsigned short* __restrict__ W1T, const float* __restrict__ b1,
    const unsigned short* __restrict__ W2T, const float* __restrict__ b2,
    const int* __restrict__ counts, const int* __restrict__ lists,
    const float* __restrict__ gvals, float* __restrict__ out)
{
    __shared__ unsigned short Xs[TM * D_];
    __shared__ unsigned short Hs[TM * H_];
    __shared__ int   tks[TM];
    __shared__ float gs[TM];

    const int bi = blockIdx.x;
    const int e = bi & 7;
    const int t0 = (bi >> 3) * TM;
    const int n = counts[e];
    if (t0 >= n) return;
    const int tid = threadIdx.x;
    const int mact = min(TM, n - t0);
    const int wave = tid >> 6;
    const int lane = tid & 63;
    const int m = lane & 15;
    const int g = lane >> 4;
    char* XsC = (char*)Xs;
    char* HsC = (char*)Hs;

    if (tid < TM) {
        if (tid < mact) {
            tks[tid] = lists[e * NT_ + t0 + tid];
            gs[tid]  = gvals[e * NT_ + t0 + tid];
        } else { tks[tid] = 0; gs[tid] = 0.f; }
    }
    __syncthreads();

    for (int idx = tid; idx < TM * (D_ / 8); idx += 256) {
        const int mm = idx >> 6;
        const int c8 = idx & 63;
        union { unsigned short u[8]; uint4 v; } p;
        if (mm < mact) {
            const float4* xr = (const float4*)(x + (size_t)tks[mm] * D_);
            const float4 v0 = xr[c8 * 2], v1 = xr[c8 * 2 + 1];
            p.u[0]=f2bf(v0.x); p.u[1]=f2bf(v0.y); p.u[2]=f2bf(v0.z); p.u[3]=f2bf(v0.w);
            p.u[4]=f2bf(v1.x); p.u[5]=f2bf(v1.y); p.u[6]=f2bf(v1.z); p.u[7]=f2bf(v1.w);
        } else {
            p.v = make_uint4(0, 0, 0, 0);
        }
        const int off = mm * (D_ * 2) + c8 * 16;
        *(uint4*)(XsC + (off ^ ((mm & 7) << 4))) = p.v;
    }
    __syncthreads();

    const int nbase = wave * 256;
    f32x4 acc1[16];
#pragma unroll
    for (int f = 0; f < 16; ++f) acc1[f] = (f32x4){0.f, 0.f, 0.f, 0.f};

    for (int k0 = 0; k0 < D_; k0 += 32) {
        const int aoff = m * (D_ * 2) + k0 * 2 + g * 16;
        const short8v a = *(const short8v*)(XsC + (aoff ^ ((m & 7) << 4)));
#pragma unroll
        for (int f = 0; f < 16; ++f) {
            const unsigned short* bp = W1T + (((size_t)(e << 10) + nbase + f * 16 + m) << 9) + k0 + g * 8;
            const short8v b = *(const short8v*)bp;
            acc1[f] = __builtin_amdgcn_mfma_f32_16x16x32_bf16(a, b, acc1[f], 0, 0, 0);
        }
    }
#pragma unroll
    for (int f = 0; f < 16; ++f) {
        const int nn = nbase + f * 16 + m;
        const float bias = b1[(e << 10) + nn];
#pragma unroll
        for (int r = 0; r < 4; ++r) {
            const int mm = g * 4 + r;
            const unsigned short hv = f2bf(fmaxf(acc1[f][r] + bias, 0.f));
            const int off = mm * (H_ * 2) + nn * 2;
            *(unsigned short*)(HsC + (off ^ ((mm & 7) << 4))) = hv;
        }
    }
    __syncthreads();

    const int obase = wave * 128;
    f32x4 acc2[8];
#pragma unroll
    for (int f = 0; f < 8; ++f) acc2[f] = (f32x4){0.f, 0.f, 0.f, 0.f};

    for (int k0 = 0; k0 < H_; k0 += 32) {
        const int aoff = m * (H_ * 2) + k0 * 2 + g * 16;
        const short8v a = *(const short8v*)(HsC + (aoff ^ ((m & 7) << 4)));
#pragma unroll
        for (int f = 0; f < 8; ++f) {
            const unsigned short* bp = W2T + (((size_t)(e << 9) + obase + f * 16 + m) << 10) + k0 + g * 8;
            const short8v b = *(const short8v*)bp;
            acc2[f] = __builtin_amdgcn_mfma_f32_16x16x32_bf16(a, b, acc2[f], 0, 0, 0);
        }
    }
#pragma unroll
    for (int f = 0; f < 8; ++f) {
        const int o = obase + f * 16 + m;
        const float bias = b2[(e << 9) + o];
#pragma unroll
        for (int r = 0; r < 4; ++r) {
            const int mm = g * 4 + r;
            const float gv = gs[mm];
            if (gv != 0.f)
                atomicAdd(out + (size_t)tks[mm] * D_ + o, (acc2[f][r] + bias) * gv);
        }
    }
}

__global__ __launch_bounds__(256) void expert_fp32(
    const float* __restrict__ x,
    const float* __restrict__ W1, const float* __restrict__ b1,
    const float* __restrict__ W2, const float* __restrict__ b2,
    const int* __restrict__ counts, const int* __restrict__ lists,
    const float* __restrict__ gvals, float* __restrict__ out)
{
    __shared__ float Xs[TM][D_];
    __shared__ float Hs[TM][H_];
    __shared__ int   tks[TM];
    __shared__ float gs[TM];

    const int e  = blockIdx.y;
    const int n  = counts[e];
    const int t0 = blockIdx.x * TM;
    if (t0 >= n) return;
    const int tid  = threadIdx.x;
    const int mact = min(TM, n - t0);

    if (tid < TM) {
        if (tid < mact) {
            tks[tid] = lists[e * NT_ + t0 + tid];
            gs[tid]  = gvals[e * NT_ + t0 + tid];
        } else { tks[tid] = 0; gs[tid] = 0.f; }
    }
    __syncthreads();
    for (int idx = tid; idx < TM * (D_ / 4); idx += 256) {
        const int mm = idx >> 7, c = idx & 127;
        float4 v = make_float4(0.f, 0.f, 0.f, 0.f);
        if (mm < mact) v = ((const float4*)(x + (size_t)tks[mm] * D_))[c];
        ((float4*)&Xs[mm][0])[c] = v;
    }
    __syncthreads();
    const float* W1e = W1 + (size_t)e * D_ * H_;
    float acc[4][TM];
#pragma unroll
    for (int jj = 0; jj < 4; ++jj)
#pragma unroll
        for (int mm = 0; mm < TM; ++mm) acc[jj][mm] = 0.f;
    for (int d4 = 0; d4 < D_ / 4; ++d4) {
        float w[4][4];
#pragma unroll
        for (int dd = 0; dd < 4; ++dd) {
            const float* wp = W1e + (size_t)(d4 * 4 + dd) * H_ + tid;
#pragma unroll
            for (int jj = 0; jj < 4; ++jj) w[dd][jj] = wp[jj * 256];
        }
#pragma unroll
        for (int mm = 0; mm < TM; ++mm) {
            const float4 xv = ((const float4*)&Xs[mm][0])[d4];
            const float* xp = &xv.x;
#pragma unroll
            for (int dd = 0; dd < 4; ++dd)
#pragma unroll
                for (int jj = 0; jj < 4; ++jj)
                    acc[jj][mm] = fmaf(xp[dd], w[dd][jj], acc[jj][mm]);
        }
    }
#pragma unroll
    for (int jj = 0; jj < 4; ++jj) {
        const int j = jj * 256 + tid;
        const float bv = b1[e * H_ + j];
#pragma unroll
        for (int mm = 0; mm < TM; ++mm) Hs[mm][j] = fmaxf(acc[jj][mm] + bv, 0.f);
    }
    __syncthreads();
    const float* W2e = W2 + (size_t)e * H_ * D_;
    float acc2[2][TM];
#pragma unroll
    for (int oo = 0; oo < 2; ++oo)
#pragma unroll
        for (int mm = 0; mm < TM; ++mm) acc2[oo][mm] = 0.f;
    for (int j4 = 0; j4 < H_ / 4; ++j4) {
        float w[4][2];
#pragma unroll
        for (int dd = 0; dd < 4; ++dd) {
            const float* wp = W2e + (size_t)(j4 * 4 + dd) * D_ + tid;
#pragma unroll
            for (int oo = 0; oo < 2; ++oo) w[dd][oo] = wp[oo * 256];
        }
#pragma unroll
        for (int mm = 0; mm < TM; ++mm) {
            const float4 hv = ((const float4*)&Hs[mm][0])[j4];
            const float* hp = &hv.x;
#pragma unroll
            for (int dd = 0; dd < 4; ++dd)
#pragma unroll
                for (int oo = 0; oo < 2; ++oo)
                    acc2[oo][mm] = fmaf(hp[dd], w[dd][oo], acc2[oo][mm]);
        }
    }
#pragma unroll
    for (int oo = 0; oo < 2; ++oo) {
        const int o = oo * 256 + tid;
        const float bv = b2[e * D_ + o];
        for (int mm = 0; mm < mact; ++mm)
            atomicAdd(out + (size_t)tks[mm] * D_ + o, (acc2[oo][mm] + bv) * gs[mm]);
    }
}

// ======================= host launcher =======================

extern "C" void kernel_launch(void* const* d_in, const int* in_sizes, int n_in,
                              void* d_out, int out_size, void* d_ws, size_t ws_size,
                              hipStream_t stream)
{
    const float* x    = (const float*)d_in[0];
    const int*   mask = (const int*)d_in[1];
    const float* wg   = (const float*)d_in[2];
    const float* W1   = (const float*)d_in[3];
    const float* b1   = (const float*)d_in[4];
    const float* W2   = (const float*)d_in[5];
    const float* b2   = (const float*)d_in[6];
    float* out = (float*)d_out;

    char* ws = (char*)d_ws;
    int*   counts = (int*)ws;                       // 32 B
    int*   lists  = (int*)(ws + 256);               // 128 KB
    float* gvals  = (float*)(ws + 256 + 131072);    // 128 KB

    // Tier A layout
    unsigned short* xbf = (unsigned short*)(ws + 0x60000);              // 4 MB
    unsigned short* W1Ta = (unsigned short*)(ws + 0x480000);            // 8 MB
    unsigned short* W2Ta = (unsigned short*)(ws + 0xC80000);            // 8 MB
    unsigned short* Hbuf = (unsigned short*)(ws + 0x1480000);           // 8448*1024*2 = 16.5 MB
    const size_t needA = 0x1480000 + (size_t)8448 * 1024 * 2;           // ~38.8 MB

    const size_t wt_bytes = (size_t)E_ * D_ * H_ * 2;
    const size_t needB = 524288 + 2 * wt_bytes;                         // ~17.3 MB

    if (ws_size >= needA) {
        prep0_kernel<<<1024, 256, 0, stream>>>(x, out, xbf, counts);
        prep1_kernel<<<3072, 256, 0, stream>>>(x, mask, wg, W1, W2,
                                               counts, lists, gvals, W1Ta, W2Ta);
        stage1_kernel<<<264 * 4, 256, 0, stream>>>(xbf, W1Ta, b1, counts, lists, Hbuf);
        stage2_kernel<<<264 * 2, 256, 0, stream>>>(Hbuf, W2Ta, b2, counts, lists, gvals, out);
    } else if (ws_size >= needB) {
        unsigned short* W1T = (unsigned short*)(ws + 524288);
        unsigned short* W2T = (unsigned short*)(ws + 524288 + wt_bytes);
        hipMemsetAsync(counts, 0, E_ * sizeof(int), stream);
        gating_kernel<<<NT_ / 4, 256, 0, stream>>>(x, mask, wg, counts, lists, gvals);
        init_out_kernel<<<(NT_ * D_) / 4 / 256, 256, 0, stream>>>(x, out);
        transpose_cvt<<<dim3(H_ / 64, D_ / 64, E_), 256, 0, stream>>>(W1, W1T, D_, H_);
        transpose_cvt<<<dim3(D_ / 64, H_ / 64, E_), 256, 0, stream>>>(W2, W2T, H_, D_);
        expert_mfma<<<(NT_ / TM) * E_, 256, 0, stream>>>(x, W1T, b1, W2T, b2,
                                                         counts, lists, gvals, out);
    } else {
        hipMemsetAsync(counts, 0, E_ * sizeof(int), stream);
        gating_kernel<<<NT_ / 4, 256, 0, stream>>>(x, mask, wg, counts, lists, gvals);
        init_out_kernel<<<(NT_ * D_) / 4 / 256, 256, 0, stream>>>(x, out);
        expert_fp32<<<dim3(NT_ / TM, E_), 256, 0, stream>>>(x, W1, b1, W2, b2,
                                                            counts, lists, gvals, out);
    }
}

// Round 4
// 127.395 us; speedup vs baseline: 3.3678x; 1.2768x over previous
//
#include <hip/hip_runtime.h>
#include <cmath>

#define B_ 8
#define S_ 512
#define D_ 512
#define H_ 1024
#define E_ 8
#define NT_ (B_*S_)   // 4096 tokens
#define TM 16         // tokens per tile (fallback path)

typedef __attribute__((ext_vector_type(8))) short short8v;
typedef __attribute__((ext_vector_type(4))) float f32x4;

__device__ inline unsigned short f2bf(float f) {
    union { float f; unsigned u; } a; a.f = f;
    unsigned u = a.u;
    return (unsigned short)((u + 0x7FFF + ((u >> 16) & 1)) >> 16);  // RNE
}

// ======================= TIER A (main path) =======================

// ---- prep0: out = x (residual), xbf = bf16(x), zero counts ----
__global__ __launch_bounds__(256) void prep0_kernel(
    const float* __restrict__ x, float* __restrict__ out,
    unsigned short* __restrict__ xbf, int* __restrict__ counts)
{
    if (blockIdx.x == 0 && threadIdx.x < E_) counts[threadIdx.x] = 0;
    const size_t i = (size_t)blockIdx.x * 256 + threadIdx.x;   // one per 8 floats
    const float4 v0 = ((const float4*)x)[i * 2];
    const float4 v1 = ((const float4*)x)[i * 2 + 1];
    ((float4*)out)[i * 2]     = v0;
    ((float4*)out)[i * 2 + 1] = v1;
    union { unsigned short u[8]; uint4 v; } p;
    p.u[0]=f2bf(v0.x); p.u[1]=f2bf(v0.y); p.u[2]=f2bf(v0.z); p.u[3]=f2bf(v0.w);
    p.u[4]=f2bf(v1.x); p.u[5]=f2bf(v1.y); p.u[6]=f2bf(v1.z); p.u[7]=f2bf(v1.w);
    ((uint4*)xbf)[i] = p.v;
}

// ---- prep1: blocks 0..1023 gating; 1024..3071 fragment-native weight repack ----
// Repacked layout per expert (K32 = K/32 k-steps):
//   chunk(F, kidx) = 1KB: lane l=(g*16+m), short j  <-  W[k = kidx*32+g*8+j][n = F*16+m]
// Stage-kernel B-frag load: chunk_base + lane*8 shorts -> 64 lanes read contiguous 1KB.
__global__ __launch_bounds__(256) void prep1_kernel(
    const float* __restrict__ x, const int* __restrict__ mask,
    const float* __restrict__ wg,
    const float* __restrict__ W1, const float* __restrict__ W2,
    int* __restrict__ counts, int* __restrict__ lists, float* __restrict__ gvals,
    unsigned short* __restrict__ W1S, unsigned short* __restrict__ W2S)
{
    const int bid = blockIdx.x;
    const int tid = threadIdx.x;
    if (bid < 1024) {
        // -------- gating: one wave per token --------
        const int wave = tid >> 6, lane = tid & 63;
        const int t = bid * 4 + wave;
        const float* xr = x + (size_t)t * D_;
        float acc[E_];
#pragma unroll
        for (int e = 0; e < E_; ++e) acc[e] = 0.f;
        for (int d = lane; d < D_; d += 64) {
            const float xv = xr[d];
            const float* wr = wg + (size_t)d * E_;
#pragma unroll
            for (int e = 0; e < E_; ++e) acc[e] += xv * wr[e];
        }
#pragma unroll
        for (int e = 0; e < E_; ++e) {
            float v = acc[e];
#pragma unroll
            for (int off = 32; off > 0; off >>= 1) v += __shfl_down(v, off, 64);
            acc[e] = v;
        }
        if (lane == 0 && mask[t] != 0) {
            int i0 = 0; float v0 = acc[0];
#pragma unroll
            for (int e = 1; e < E_; ++e) if (acc[e] > v0) { v0 = acc[e]; i0 = e; }
            int i1 = -1; float v1 = -INFINITY;
#pragma unroll
            for (int e = 0; e < E_; ++e) if (e != i0 && acc[e] > v1) { v1 = acc[e]; i1 = e; }
            const float ex = __expf(v1 - v0);
            const float denom = 1.f + ex;
            const int p0 = atomicAdd(&counts[i0], 1);
            lists[i0 * NT_ + p0] = t; gvals[i0 * NT_ + p0] = 1.f / denom;
            const int p1 = atomicAdd(&counts[i1], 1);
            lists[i1 * NT_ + p1] = t; gvals[i1 * NT_ + p1] = ex / denom;
        }
    } else {
        // -------- 64x64 fragment-native repack tile --------
        __shared__ unsigned short tT[64][68];   // pad 68: col-gather 2-way (free)
        const float* s; unsigned short* dstE; int C, K32, kt, nt;
        if (bid < 2048) {
            const int t = bid - 1024; const int e = t >> 7; const int rem = t & 127;
            kt = rem >> 4; nt = rem & 15;          // W1: [512 k][1024 n]
            C = H_; K32 = D_ >> 5;                 // K32 = 16
            s = W1 + (size_t)e * D_ * H_ + (size_t)(kt * 64) * C + nt * 64;
            dstE = W1S + ((size_t)e << 19);
        } else {
            const int t = bid - 2048; const int e = t >> 7; const int rem = t & 127;
            kt = rem >> 3; nt = rem & 7;           // W2: [1024 k][512 n]
            C = D_; K32 = H_ >> 5;                 // K32 = 32
            s = W2 + (size_t)e * H_ * D_ + (size_t)(kt * 64) * C + nt * 64;
            dstE = W2S + ((size_t)e << 19);
        }
        const int q = tid & 15, r = tid >> 4;
#pragma unroll
        for (int pass = 0; pass < 4; ++pass) {
            const int k = r + pass * 16;
            const float4 v = *(const float4*)(s + (size_t)k * C + q * 4);
            unsigned short* tp = &tT[k][q * 4];
            tp[0] = f2bf(v.x); tp[1] = f2bf(v.y); tp[2] = f2bf(v.z); tp[3] = f2bf(v.w);
        }
        __syncthreads();
        // write phase: each wave emits one contiguous 1KB chunk per half
        const int l = tid & 63;
        const int g = l >> 4, m = l & 15;
#pragma unroll
        for (int half = 0; half < 2; ++half) {
            const int c = (tid >> 6) + half * 4;   // chunk 0..7 within tile
            const int nfl = c >> 1, k0l = c & 1;
            union { unsigned short u[8]; uint4 v; } p;
#pragma unroll
            for (int j = 0; j < 8; ++j)
                p.u[j] = tT[k0l * 32 + g * 8 + j][nfl * 16 + m];
            const int F = nt * 4 + nfl;
            const int kidx = kt * 2 + k0l;
            *(uint4*)(dstE + ((size_t)(F * K32 + kidx) << 9) + l * 8) = p.v;
        }
    }
}

// ---- per-block (expert, tile) mapping from counts prefix ----
__device__ inline bool find_tile(const int* __restrict__ counts, int tflat,
                                 int& e, int& t0, int& off, int& n_e)
{
    int cum = 0, offacc = 0; e = -1;
#pragma unroll
    for (int i = 0; i < E_; ++i) {
        const int c = counts[i];
        const int t = (c + 31) >> 5;
        if (e < 0 && tflat < cum + t) { e = i; t0 = (tflat - cum) << 5; off = offacc; n_e = c; }
        cum += t; offacc += c;
    }
    return e >= 0;
}

// ---- stage1: H[slot][h] = relu(Xbf[tok] @ W1 + b1), streaming MFMA ----
// grid.x = 264*4; block tile = 32 tokens x 256 cols; wave tile = 32x64
__global__ __launch_bounds__(256) void stage1_kernel(
    const unsigned short* __restrict__ xbf,
    const unsigned short* __restrict__ W1S, const float* __restrict__ b1,
    const int* __restrict__ counts, const int* __restrict__ lists,
    unsigned short* __restrict__ Hbuf)
{
    const int nb = blockIdx.x & 3;
    const int tflat = blockIdx.x >> 2;
    int e, t0, off, n_e;
    if (!find_tile(counts, tflat, e, t0, off, n_e)) return;
    const int mact = min(32, n_e - t0);
    __shared__ int tks[32];
    const int tid = threadIdx.x;
    if (tid < 32) tks[tid] = lists[e * NT_ + t0 + min(tid, mact - 1)];
    __syncthreads();

    const int wave = tid >> 6, lane = tid & 63, m = lane & 15, g = lane >> 4;
    const int colbase = nb * 256 + wave * 64;

    const unsigned short* a0p = xbf + ((size_t)tks[m] << 9) + (g << 3);
    const unsigned short* a1p = xbf + ((size_t)tks[16 + m] << 9) + (g << 3);
    // frag-native B: chunk stride per F = K32*512 = 8192 shorts (<<13)
    const unsigned short* Bb = W1S + ((size_t)e << 19)
                             + ((size_t)(nb * 16 + wave * 4) << 13) + (lane << 3);

    f32x4 acc[2][4];
#pragma unroll
    for (int i = 0; i < 2; ++i)
#pragma unroll
        for (int f = 0; f < 4; ++f) acc[i][f] = (f32x4){0.f, 0.f, 0.f, 0.f};

#pragma unroll 2
    for (int kk = 0; kk < 16; ++kk) {
        const short8v a0 = *(const short8v*)(a0p + (kk << 5));
        const short8v a1 = *(const short8v*)(a1p + (kk << 5));
        const short8v b0  = *(const short8v*)(Bb + (kk << 9));
        const short8v b1v = *(const short8v*)(Bb + (1 << 13) + (kk << 9));
        const short8v b2v = *(const short8v*)(Bb + (2 << 13) + (kk << 9));
        const short8v b3  = *(const short8v*)(Bb + (3 << 13) + (kk << 9));
        acc[0][0] = __builtin_amdgcn_mfma_f32_16x16x32_bf16(a0, b0,  acc[0][0], 0, 0, 0);
        acc[1][0] = __builtin_amdgcn_mfma_f32_16x16x32_bf16(a1, b0,  acc[1][0], 0, 0, 0);
        acc[0][1] = __builtin_amdgcn_mfma_f32_16x16x32_bf16(a0, b1v, acc[0][1], 0, 0, 0);
        acc[1][1] = __builtin_amdgcn_mfma_f32_16x16x32_bf16(a1, b1v, acc[1][1], 0, 0, 0);
        acc[0][2] = __builtin_amdgcn_mfma_f32_16x16x32_bf16(a0, b2v, acc[0][2], 0, 0, 0);
        acc[1][2] = __builtin_amdgcn_mfma_f32_16x16x32_bf16(a1, b2v, acc[1][2], 0, 0, 0);
        acc[0][3] = __builtin_amdgcn_mfma_f32_16x16x32_bf16(a0, b3,  acc[0][3], 0, 0, 0);
        acc[1][3] = __builtin_amdgcn_mfma_f32_16x16x32_bf16(a1, b3,  acc[1][3], 0, 0, 0);
    }

#pragma unroll
    for (int f = 0; f < 4; ++f) {
        const int col = colbase + f * 16 + m;
        const float bias = b1[(e << 10) + col];
#pragma unroll
        for (int i = 0; i < 2; ++i)
#pragma unroll
            for (int r = 0; r < 4; ++r) {
                const int row = i * 16 + g * 4 + r;
                if (row < mact)
                    Hbuf[((size_t)(off + t0 + row) << 10) + col] =
                        f2bf(fmaxf(acc[i][f][r] + bias, 0.f));
            }
    }
}

// ---- stage2: out[tok] += gate * (H[slot] @ W2 + b2), streaming MFMA ----
// grid.x = 264*2; block tile = 32 rows x 256 cols; wave tile = 32x64
__global__ __launch_bounds__(256) void stage2_kernel(
    const unsigned short* __restrict__ Hbuf,
    const unsigned short* __restrict__ W2S, const float* __restrict__ b2,
    const int* __restrict__ counts, const int* __restrict__ lists,
    const float* __restrict__ gvals, float* __restrict__ out)
{
    const int nb = blockIdx.x & 1;
    const int tflat = blockIdx.x >> 1;
    int e, t0, off, n_e;
    if (!find_tile(counts, tflat, e, t0, off, n_e)) return;
    const int mact = min(32, n_e - t0);
    __shared__ int tks[32];
    __shared__ float gsh[32];
    const int tid = threadIdx.x;
    if (tid < 32) {
        const int idx = min(tid, mact - 1);
        tks[tid] = lists[e * NT_ + t0 + idx];
        gsh[tid] = gvals[e * NT_ + t0 + idx];
    }
    __syncthreads();

    const int wave = tid >> 6, lane = tid & 63, m = lane & 15, g = lane >> 4;
    const int colbase = nb * 256 + wave * 64;

    const unsigned short* a0p = Hbuf + ((size_t)(off + t0 + m) << 10) + (g << 3);
    const unsigned short* a1p = Hbuf + ((size_t)(off + t0 + 16 + m) << 10) + (g << 3);
    // frag-native B: chunk stride per F = K32*512 = 16384 shorts (<<14)
    const unsigned short* Bb = W2S + ((size_t)e << 19)
                             + ((size_t)(nb * 16 + wave * 4) << 14) + (lane << 3);

    f32x4 acc[2][4];
#pragma unroll
    for (int i = 0; i < 2; ++i)
#pragma unroll
        for (int f = 0; f < 4; ++f) acc[i][f] = (f32x4){0.f, 0.f, 0.f, 0.f};

#pragma unroll 2
    for (int kk = 0; kk < 32; ++kk) {
        const short8v a0 = *(const short8v*)(a0p + (kk << 5));
        const short8v a1 = *(const short8v*)(a1p + (kk << 5));
        const short8v b0  = *(const short8v*)(Bb + (kk << 9));
        const short8v b1v = *(const short8v*)(Bb + (1 << 14) + (kk << 9));
        const short8v b2v = *(const short8v*)(Bb + (2 << 14) + (kk << 9));
        const short8v b3  = *(const short8v*)(Bb + (3 << 14) + (kk << 9));
        acc[0][0] = __builtin_amdgcn_mfma_f32_16x16x32_bf16(a0, b0,  acc[0][0], 0, 0, 0);
        acc[1][0] = __builtin_amdgcn_mfma_f32_16x16x32_bf16(a1, b0,  acc[1][0], 0, 0, 0);
        acc[0][1] = __builtin_amdgcn_mfma_f32_16x16x32_bf16(a0, b1v, acc[0][1], 0, 0, 0);
        acc[1][1] = __builtin_amdgcn_mfma_f32_16x16x32_bf16(a1, b1v, acc[1][1], 0, 0, 0);
        acc[0][2] = __builtin_amdgcn_mfma_f32_16x16x32_bf16(a0, b2v, acc[0][2], 0, 0, 0);
        acc[1][2] = __builtin_amdgcn_mfma_f32_16x16x32_bf16(a1, b2v, acc[1][2], 0, 0, 0);
        acc[0][3] = __builtin_amdgcn_mfma_f32_16x16x32_bf16(a0, b3,  acc[0][3], 0, 0, 0);
        acc[1][3] = __builtin_amdgcn_mfma_f32_16x16x32_bf16(a1, b3,  acc[1][3], 0, 0, 0);
    }

#pragma unroll
    for (int f = 0; f < 4; ++f) {
        const int col = colbase + f * 16 + m;
        const float bias = b2[(e << 9) + col];
#pragma unroll
        for (int i = 0; i < 2; ++i)
#pragma unroll
            for (int r = 0; r < 4; ++r) {
                const int row = i * 16 + g * 4 + r;
                if (row < mact)
                    atomicAdd(out + ((size_t)tks[row] << 9) + col,
                              (acc[i][f][r] + bias) * gsh[row]);
            }
    }
}

// ======================= TIER B/C fallbacks =======================

__global__ __launch_bounds__(256) void gating_kernel(
    const float* __restrict__ x, const int* __restrict__ mask,
    const float* __restrict__ wg, int* __restrict__ counts,
    int* __restrict__ lists, float* __restrict__ gvals)
{
    const int wave = threadIdx.x >> 6;
    const int lane = threadIdx.x & 63;
    const int t = blockIdx.x * 4 + wave;
    const float* xr = x + (size_t)t * D_;
    float acc[E_];
#pragma unroll
    for (int e = 0; e < E_; ++e) acc[e] = 0.f;
    for (int d = lane; d < D_; d += 64) {
        const float xv = xr[d];
        const float* wr = wg + (size_t)d * E_;
#pragma unroll
        for (int e = 0; e < E_; ++e) acc[e] += xv * wr[e];
    }
#pragma unroll
    for (int e = 0; e < E_; ++e) {
        float v = acc[e];
#pragma unroll
        for (int off = 32; off > 0; off >>= 1) v += __shfl_down(v, off, 64);
        acc[e] = v;
    }
    if (lane == 0 && mask[t] != 0) {
        int i0 = 0; float v0 = acc[0];
#pragma unroll
        for (int e = 1; e < E_; ++e) if (acc[e] > v0) { v0 = acc[e]; i0 = e; }
        int i1 = -1; float v1 = -INFINITY;
#pragma unroll
        for (int e = 0; e < E_; ++e) if (e != i0 && acc[e] > v1) { v1 = acc[e]; i1 = e; }
        const float ex = __expf(v1 - v0);
        const float denom = 1.f + ex;
        const int p0 = atomicAdd(&counts[i0], 1);
        lists[i0 * NT_ + p0] = t; gvals[i0 * NT_ + p0] = 1.f / denom;
        const int p1 = atomicAdd(&counts[i1], 1);
        lists[i1 * NT_ + p1] = t; gvals[i1 * NT_ + p1] = ex / denom;
    }
}

__global__ __launch_bounds__(256) void init_out_kernel(
    const float* __restrict__ x, float* __restrict__ out)
{
    const size_t i = (size_t)blockIdx.x * blockDim.x + threadIdx.x;
    ((float4*)out)[i] = ((const float4*)x)[i];
}

__global__ __launch_bounds__(256) void transpose_cvt(
    const float* __restrict__ src, unsigned short* __restrict__ dst, int R, int C)
{
    __shared__ unsigned short t[64][72];
    const float* s = src + (size_t)blockIdx.z * R * C;
    unsigned short* d = dst + (size_t)blockIdx.z * R * C;
    const int r0 = blockIdx.y * 64, c0 = blockIdx.x * 64;
    const int tc = threadIdx.x & 63;
    const int tr = threadIdx.x >> 6;
#pragma unroll
    for (int i = 0; i < 16; ++i) {
        const int r = tr + i * 4;
        t[r][tc] = f2bf(s[(size_t)(r0 + r) * C + c0 + tc]);
    }
    __syncthreads();
    const int c = threadIdx.x >> 2;
    const int ch = threadIdx.x & 3;
#pragma unroll
    for (int half = 0; half < 2; ++half) {
        union { unsigned short u[8]; uint4 v; } p;
#pragma unroll
        for (int k = 0; k < 8; ++k) p.u[k] = t[ch * 16 + half * 8 + k][c];
        *(uint4*)(d + (size_t)(c0 + c) * R + r0 + ch * 16 + half * 8) = p.v;
    }
}

__global__ __launch_bounds__(256) void expert_mfma(
    const float* __restrict__ x,
    const unsigned short* __restrict__ W1T, const float* __restrict__ b1,
    const unsigned short* __restrict__ W2T, const float* __restrict__ b2,
    const int* __restrict__ counts, const int* __restrict__ lists,
    const float* __restrict__ gvals, float* __restrict__ out)
{
    __shared__ unsigned short Xs[TM * D_];
    __shared__ unsigned short Hs[TM * H_];
    __shared__ int   tks[TM];
    __shared__ float gs[TM];

    const int bi = blockIdx.x;
    const int e = bi & 7;
    const int t0 = (bi >> 3) * TM;
    const int n = counts[e];
    if (t0 >= n) return;
    const int tid = threadIdx.x;
    const int mact = min(TM, n - t0);
    const int wave = tid >> 6;
    const int lane = tid & 63;
    const int m = lane & 15;
    const int g = lane >> 4;
    char* XsC = (char*)Xs;
    char* HsC = (char*)Hs;

    if (tid < TM) {
        if (tid < mact) {
            tks[tid] = lists[e * NT_ + t0 + tid];
            gs[tid]  = gvals[e * NT_ + t0 + tid];
        } else { tks[tid] = 0; gs[tid] = 0.f; }
    }
    __syncthreads();

    for (int idx = tid; idx < TM * (D_ / 8); idx += 256) {
        const int mm = idx >> 6;
        const int c8 = idx & 63;
        union { unsigned short u[8]; uint4 v; } p;
        if (mm < mact) {
            const float4* xr = (const float4*)(x + (size_t)tks[mm] * D_);
            const float4 v0 = xr[c8 * 2], v1 = xr[c8 * 2 + 1];
            p.u[0]=f2bf(v0.x); p.u[1]=f2bf(v0.y); p.u[2]=f2bf(v0.z); p.u[3]=f2bf(v0.w);
            p.u[4]=f2bf(v1.x); p.u[5]=f2bf(v1.y); p.u[6]=f2bf(v1.z); p.u[7]=f2bf(v1.w);
        } else {
            p.v = make_uint4(0, 0, 0, 0);
        }
        const int off = mm * (D_ * 2) + c8 * 16;
        *(uint4*)(XsC + (off ^ ((mm & 7) << 4))) = p.v;
    }
    __syncthreads();

    const int nbase = wave * 256;
    f32x4 acc1[16];
#pragma unroll
    for (int f = 0; f < 16; ++f) acc1[f] = (f32x4){0.f, 0.f, 0.f, 0.f};

    for (int k0 = 0; k0 < D_; k0 += 32) {
        const int aoff = m * (D_ * 2) + k0 * 2 + g * 16;
        const short8v a = *(const short8v*)(XsC + (aoff ^ ((m & 7) << 4)));
#pragma unroll
        for (int f = 0; f < 16; ++f) {
            const unsigned short* bp = W1T + (((size_t)(e << 10) + nbase + f * 16 + m) << 9) + k0 + g * 8;
            const short8v b = *(const short8v*)bp;
            acc1[f] = __builtin_amdgcn_mfma_f32_16x16x32_bf16(a, b, acc1[f], 0, 0, 0);
        }
    }
#pragma unroll
    for (int f = 0; f < 16; ++f) {
        const int nn = nbase + f * 16 + m;
        const float bias = b1[(e << 10) + nn];
#pragma unroll
        for (int r = 0; r < 4; ++r) {
            const int mm = g * 4 + r;
            const unsigned short hv = f2bf(fmaxf(acc1[f][r] + bias, 0.f));
            const int off = mm * (H_ * 2) + nn * 2;
            *(unsigned short*)(HsC + (off ^ ((mm & 7) << 4))) = hv;
        }
    }
    __syncthreads();

    const int obase = wave * 128;
    f32x4 acc2[8];
#pragma unroll
    for (int f = 0; f < 8; ++f) acc2[f] = (f32x4){0.f, 0.f, 0.f, 0.f};

    for (int k0 = 0; k0 < H_; k0 += 32) {
        const int aoff = m * (H_ * 2) + k0 * 2 + g * 16;
        const short8v a = *(const short8v*)(HsC + (aoff ^ ((m & 7) << 4)));
#pragma unroll
        for (int f = 0; f < 8; ++f) {
            const unsigned short* bp = W2T + (((size_t)(e << 9) + obase + f * 16 + m) << 10) + k0 + g * 8;
            const short8v b = *(const short8v*)bp;
            acc2[f] = __builtin_amdgcn_mfma_f32_16x16x32_bf16(a, b, acc2[f], 0, 0, 0);
        }
    }
#pragma unroll
    for (int f = 0; f < 8; ++f) {
        const int o = obase + f * 16 + m;
        const float bias = b2[(e << 9) + o];
#pragma unroll
        for (int r = 0; r < 4; ++r) {
            const int mm = g * 4 + r;
            const float gv = gs[mm];
            if (gv != 0.f)
                atomicAdd(out + (size_t)tks[mm] * D_ + o, (acc2[f][r] + bias) * gv);
        }
    }
}

__global__ __launch_bounds__(256) void expert_fp32(
    const float* __restrict__ x,
    const float* __restrict__ W1, const float* __restrict__ b1,
    const float* __restrict__ W2, const float* __restrict__ b2,
    const int* __restrict__ counts, const int* __restrict__ lists,
    const float* __restrict__ gvals, float* __restrict__ out)
{
    __shared__ float Xs[TM][D_];
    __shared__ float Hs[TM][H_];
    __shared__ int   tks[TM];
    __shared__ float gs[TM];

    const int e  = blockIdx.y;
    const int n  = counts[e];
    const int t0 = blockIdx.x * TM;
    if (t0 >= n) return;
    const int tid  = threadIdx.x;
    const int mact = min(TM, n - t0);

    if (tid < TM) {
        if (tid < mact) {
            tks[tid] = lists[e * NT_ + t0 + tid];
            gs[tid]  = gvals[e * NT_ + t0 + tid];
        } else { tks[tid] = 0; gs[tid] = 0.f; }
    }
    __syncthreads();
    for (int idx = tid; idx < TM * (D_ / 4); idx += 256) {
        const int mm = idx >> 7, c = idx & 127;
        float4 v = make_float4(0.f, 0.f, 0.f, 0.f);
        if (mm < mact) v = ((const float4*)(x + (size_t)tks[mm] * D_))[c];
        ((float4*)&Xs[mm][0])[c] = v;
    }
    __syncthreads();
    const float* W1e = W1 + (size_t)e * D_ * H_;
    float acc[4][TM];
#pragma unroll
    for (int jj = 0; jj < 4; ++jj)
#pragma unroll
        for (int mm = 0; mm < TM; ++mm) acc[jj][mm] = 0.f;
    for (int d4 = 0; d4 < D_ / 4; ++d4) {
        float w[4][4];
#pragma unroll
        for (int dd = 0; dd < 4; ++dd) {
            const float* wp = W1e + (size_t)(d4 * 4 + dd) * H_ + tid;
#pragma unroll
            for (int jj = 0; jj < 4; ++jj) w[dd][jj] = wp[jj * 256];
        }
#pragma unroll
        for (int mm = 0; mm < TM; ++mm) {
            const float4 xv = ((const float4*)&Xs[mm][0])[d4];
            const float* xp = &xv.x;
#pragma unroll
            for (int dd = 0; dd < 4; ++dd)
#pragma unroll
                for (int jj = 0; jj < 4; ++jj)
                    acc[jj][mm] = fmaf(xp[dd], w[dd][jj], acc[jj][mm]);
        }
    }
#pragma unroll
    for (int jj = 0; jj < 4; ++jj) {
        const int j = jj * 256 + tid;
        const float bv = b1[e * H_ + j];
#pragma unroll
        for (int mm = 0; mm < TM; ++mm) Hs[mm][j] = fmaxf(acc[jj][mm] + bv, 0.f);
    }
    __syncthreads();
    const float* W2e = W2 + (size_t)e * H_ * D_;
    float acc2[2][TM];
#pragma unroll
    for (int oo = 0; oo < 2; ++oo)
#pragma unroll
        for (int mm = 0; mm < TM; ++mm) acc2[oo][mm] = 0.f;
    for (int j4 = 0; j4 < H_ / 4; ++j4) {
        float w[4][2];
#pragma unroll
        for (int dd = 0; dd < 4; ++dd) {
            const float* wp = W2e + (size_t)(j4 * 4 + dd) * D_ + tid;
#pragma unroll
            for (int oo = 0; oo < 2; ++oo) w[dd][oo] = wp[oo * 256];
        }
#pragma unroll
        for (int mm = 0; mm < TM; ++mm) {
            const float4 hv = ((const float4*)&Hs[mm][0])[j4];
            const float* hp = &hv.x;
#pragma unroll
            for (int dd = 0; dd < 4; ++dd)
#pragma unroll
                for (int oo = 0; oo < 2; ++oo)
                    acc2[oo][mm] = fmaf(hp[dd], w[dd][oo], acc2[oo][mm]);
        }
    }
#pragma unroll
    for (int oo = 0; oo < 2; ++oo) {
        const int o = oo * 256 + tid;
        const float bv = b2[e * D_ + o];
        for (int mm = 0; mm < mact; ++mm)
            atomicAdd(out + (size_t)tks[mm] * D_ + o, (acc2[oo][mm] + bv) * gs[mm]);
    }
}

// ======================= host launcher =======================

extern "C" void kernel_launch(void* const* d_in, const int* in_sizes, int n_in,
                              void* d_out, int out_size, void* d_ws, size_t ws_size,
                              hipStream_t stream)
{
    const float* x    = (const float*)d_in[0];
    const int*   mask = (const int*)d_in[1];
    const float* wg   = (const float*)d_in[2];
    const float* W1   = (const float*)d_in[3];
    const float* b1   = (const float*)d_in[4];
    const float* W2   = (const float*)d_in[5];
    const float* b2   = (const float*)d_in[6];
    float* out = (float*)d_out;

    char* ws = (char*)d_ws;
    int*   counts = (int*)ws;                       // 32 B
    int*   lists  = (int*)(ws + 256);               // 128 KB
    float* gvals  = (float*)(ws + 256 + 131072);    // 128 KB

    // Tier A layout
    unsigned short* xbf  = (unsigned short*)(ws + 0x60000);             // 4 MB
    unsigned short* W1Sa = (unsigned short*)(ws + 0x480000);            // 8 MB
    unsigned short* W2Sa = (unsigned short*)(ws + 0xC80000);            // 8 MB
    unsigned short* Hbuf = (unsigned short*)(ws + 0x1480000);           // 16.5 MB
    const size_t needA = 0x1480000 + (size_t)8448 * 1024 * 2;           // ~38.8 MB

    const size_t wt_bytes = (size_t)E_ * D_ * H_ * 2;
    const size_t needB = 524288 + 2 * wt_bytes;                         // ~17.3 MB

    if (ws_size >= needA) {
        prep0_kernel<<<1024, 256, 0, stream>>>(x, out, xbf, counts);
        prep1_kernel<<<3072, 256, 0, stream>>>(x, mask, wg, W1, W2,
                                               counts, lists, gvals, W1Sa, W2Sa);
        stage1_kernel<<<264 * 4, 256, 0, stream>>>(xbf, W1Sa, b1, counts, lists, Hbuf);
        stage2_kernel<<<264 * 2, 256, 0, stream>>>(Hbuf, W2Sa, b2, counts, lists, gvals, out);
    } else if (ws_size >= needB) {
        unsigned short* W1T = (unsigned short*)(ws + 524288);
        unsigned short* W2T = (unsigned short*)(ws + 524288 + wt_bytes);
        hipMemsetAsync(counts, 0, E_ * sizeof(int), stream);
        gating_kernel<<<NT_ / 4, 256, 0, stream>>>(x, mask, wg, counts, lists, gvals);
        init_out_kernel<<<(NT_ * D_) / 4 / 256, 256, 0, stream>>>(x, out);
        transpose_cvt<<<dim3(H_ / 64, D_ / 64, E_), 256, 0, stream>>>(W1, W1T, D_, H_);
        transpose_cvt<<<dim3(D_ / 64, H_ / 64, E_), 256, 0, stream>>>(W2, W2T, H_, D_);
        expert_mfma<<<(NT_ / TM) * E_, 256, 0, stream>>>(x, W1T, b1, W2T, b2,
                                                         counts, lists, gvals, out);
    } else {
        hipMemsetAsync(counts, 0, E_ * sizeof(int), stream);
        gating_kernel<<<NT_ / 4, 256, 0, stream>>>(x, mask, wg, counts, lists, gvals);
        init_out_kernel<<<(NT_ * D_) / 4 / 256, 256, 0, stream>>>(x, out);
        expert_fp32<<<dim3(NT_ / TM, E_), 256, 0, stream>>>(x, W1, b1, W2, b2,
                                                            counts, lists, gvals, out);
    }
}

// Round 5
// 116.290 us; speedup vs baseline: 3.6894x; 1.0955x over previous
//
#include <hip/hip_runtime.h>
#include <cmath>

#define B_ 8
#define S_ 512
#define D_ 512
#define H_ 1024
#define E_ 8
#define NT_ (B_*S_)   // 4096 tokens
#define TM 16         // tokens per tile (fallback path)

typedef __attribute__((ext_vector_type(8))) short short8v;
typedef __attribute__((ext_vector_type(4))) float f32x4;

__device__ inline unsigned short f2bf(float f) {
    union { float f; unsigned u; } a; a.f = f;
    unsigned u = a.u;
    return (unsigned short)((u + 0x7FFF + ((u >> 16) & 1)) >> 16);  // RNE
}

// ======================= TIER A (main path) =======================

// ---- prep0g: out = x, xbf = bf16(x), and per-token gating (NO atomics) ----
// grid 1024 x 256: wave w of block b handles token t = 4b+w (512 floats).
__global__ __launch_bounds__(256) void prep0g_kernel(
    const float* __restrict__ x, const int* __restrict__ mask,
    const float* __restrict__ wg,
    float* __restrict__ out, unsigned short* __restrict__ xbf,
    uchar2* __restrict__ tokE, float2* __restrict__ tokG)
{
    const int tid = threadIdx.x, wave = tid >> 6, lane = tid & 63;
    const int t = blockIdx.x * 4 + wave;
    const float4* xr = (const float4*)(x + ((size_t)t << 9));
    const float4 v0 = xr[lane];        // floats [4*lane, 4*lane+4)
    const float4 v1 = xr[lane + 64];   // floats [256+4*lane, ...)
    float4* orow = (float4*)(out + ((size_t)t << 9));
    orow[lane] = v0; orow[lane + 64] = v1;
    union { unsigned short u[4]; uint2 w; } pa, pb;
    pa.u[0]=f2bf(v0.x); pa.u[1]=f2bf(v0.y); pa.u[2]=f2bf(v0.z); pa.u[3]=f2bf(v0.w);
    pb.u[0]=f2bf(v1.x); pb.u[1]=f2bf(v1.y); pb.u[2]=f2bf(v1.z); pb.u[3]=f2bf(v1.w);
    uint2* xrow = (uint2*)(xbf + ((size_t)t << 9));
    xrow[lane] = pa.w; xrow[lane + 64] = pb.w;

    // logits partials over this lane's 8 d's
    float acc[E_];
#pragma unroll
    for (int e = 0; e < E_; ++e) acc[e] = 0.f;
    const int d0 = lane * 4;
#pragma unroll
    for (int dd = 0; dd < 4; ++dd) {
        const float xa = (&v0.x)[dd], xb = (&v1.x)[dd];
        const float4 wa0 = *(const float4*)(wg + (size_t)(d0 + dd) * 8);
        const float4 wa1 = *(const float4*)(wg + (size_t)(d0 + dd) * 8 + 4);
        const float4 wb0 = *(const float4*)(wg + (size_t)(256 + d0 + dd) * 8);
        const float4 wb1 = *(const float4*)(wg + (size_t)(256 + d0 + dd) * 8 + 4);
        acc[0] += xa * wa0.x + xb * wb0.x;
        acc[1] += xa * wa0.y + xb * wb0.y;
        acc[2] += xa * wa0.z + xb * wb0.z;
        acc[3] += xa * wa0.w + xb * wb0.w;
        acc[4] += xa * wa1.x + xb * wb1.x;
        acc[5] += xa * wa1.y + xb * wb1.y;
        acc[6] += xa * wa1.z + xb * wb1.z;
        acc[7] += xa * wa1.w + xb * wb1.w;
    }
#pragma unroll
    for (int e = 0; e < E_; ++e) {
        float v = acc[e];
#pragma unroll
        for (int off = 32; off > 0; off >>= 1) v += __shfl_xor(v, off, 64);
        acc[e] = v;
    }
    if (lane == 0) {
        if (mask[t] != 0) {
            int i0 = 0; float v0m = acc[0];
#pragma unroll
            for (int e = 1; e < E_; ++e) if (acc[e] > v0m) { v0m = acc[e]; i0 = e; }
            int i1 = -1; float v1m = -INFINITY;
#pragma unroll
            for (int e = 0; e < E_; ++e) if (e != i0 && acc[e] > v1m) { v1m = acc[e]; i1 = e; }
            const float ex = __expf(v1m - v0m);
            const float denom = 1.f + ex;
            tokE[t] = make_uchar2((unsigned char)i0, (unsigned char)i1);
            tokG[t] = make_float2(1.f / denom, ex / denom);
        } else {
            tokE[t] = make_uchar2(255, 255);
        }
    }
}

// ---- prep1: block 0 = build_lists (counting sort, no atomics);
//      blocks 1..1024 = W1 repack tiles; 1025..2048 = W2 repack tiles ----
// Repacked layout per expert: chunk(F,kidx)=1KB; lane l=(g*16+m), short j <-
//   W[k=kidx*32+g*8+j][n=F*16+m]; B-frag load = 64 lanes x 16B contiguous.
__global__ __launch_bounds__(256) void prep1_kernel(
    const float* __restrict__ W1, const float* __restrict__ W2,
    unsigned short* __restrict__ W1S, unsigned short* __restrict__ W2S,
    const uchar2* __restrict__ tokE, const float2* __restrict__ tokG,
    int* __restrict__ counts, int* __restrict__ lists, float* __restrict__ gvals)
{
    __shared__ unsigned short tT[64][68];
    __shared__ int waveTot[4][E_];
    __shared__ int waveBase[4][E_];
    const int bid = blockIdx.x;
    const int tid = threadIdx.x;

    if (bid == 0) {
        // -------- deterministic counting sort: 256 thr x 16 tokens --------
        const int lane = tid & 63, wave = tid >> 6;
        int h[E_];
#pragma unroll
        for (int e = 0; e < E_; ++e) h[e] = 0;
#pragma unroll
        for (int j = 0; j < 16; ++j) {
            const uchar2 ee = tokE[tid * 16 + j];
#pragma unroll
            for (int e = 0; e < E_; ++e) h[e] += (ee.x == e) + (ee.y == e);
        }
        int pre[E_];
#pragma unroll
        for (int e = 0; e < E_; ++e) {
            int v = h[e];
#pragma unroll
            for (int off = 1; off < 64; off <<= 1) {
                const int o = __shfl_up(v, off, 64);
                if (lane >= off) v += o;
            }
            pre[e] = v - h[e];
            if (lane == 63) waveTot[wave][e] = v;
        }
        __syncthreads();
        if (tid < E_) {
            int s = 0;
#pragma unroll
            for (int w = 0; w < 4; ++w) { const int v = waveTot[w][tid]; waveBase[w][tid] = s; s += v; }
            counts[tid] = s;
        }
        __syncthreads();
        int base[E_], cnt[E_];
#pragma unroll
        for (int e = 0; e < E_; ++e) { base[e] = waveBase[wave][e] + pre[e]; cnt[e] = 0; }
#pragma unroll
        for (int j = 0; j < 16; ++j) {
            const int t = tid * 16 + j;
            const uchar2 ee = tokE[t];
            if (ee.x == 255) continue;
            const float2 gg = tokG[t];
#pragma unroll
            for (int e = 0; e < E_; ++e) {
                if (ee.x == e) { const int s = base[e] + cnt[e]; lists[e * NT_ + s] = t; gvals[e * NT_ + s] = gg.x; cnt[e]++; }
                if (ee.y == e) { const int s = base[e] + cnt[e]; lists[e * NT_ + s] = t; gvals[e * NT_ + s] = gg.y; cnt[e]++; }
            }
        }
        return;
    }

    // -------- 64x64 fragment-native repack tile --------
    const float* s; unsigned short* dstE; int C, K32, kt, nt;
    if (bid <= 1024) {
        const int t = bid - 1; const int e = t >> 7; const int rem = t & 127;
        kt = rem >> 4; nt = rem & 15;          // W1: [512 k][1024 n]
        C = H_; K32 = D_ >> 5;                 // 16
        s = W1 + (size_t)e * D_ * H_ + (size_t)(kt * 64) * C + nt * 64;
        dstE = W1S + ((size_t)e << 19);
    } else {
        const int t = bid - 1025; const int e = t >> 7; const int rem = t & 127;
        kt = rem >> 3; nt = rem & 7;           // W2: [1024 k][512 n]
        C = D_; K32 = H_ >> 5;                 // 32
        s = W2 + (size_t)e * H_ * D_ + (size_t)(kt * 64) * C + nt * 64;
        dstE = W2S + ((size_t)e << 19);
    }
    const int q = tid & 15, r = tid >> 4;
    float4 va[4];
#pragma unroll
    for (int pass = 0; pass < 4; ++pass)
        va[pass] = *(const float4*)(s + (size_t)(r + pass * 16) * C + q * 4);
#pragma unroll
    for (int pass = 0; pass < 4; ++pass) {
        unsigned short* tp = &tT[r + pass * 16][q * 4];
        tp[0] = f2bf(va[pass].x); tp[1] = f2bf(va[pass].y);
        tp[2] = f2bf(va[pass].z); tp[3] = f2bf(va[pass].w);
    }
    __syncthreads();
    const int l = tid & 63;
    const int g = l >> 4, m = l & 15;
#pragma unroll
    for (int half = 0; half < 2; ++half) {
        const int c = (tid >> 6) + half * 4;   // chunk 0..7 within tile
        const int nfl = c >> 1, k0l = c & 1;
        union { unsigned short u[8]; uint4 v; } p;
#pragma unroll
        for (int j = 0; j < 8; ++j)
            p.u[j] = tT[k0l * 32 + g * 8 + j][nfl * 16 + m];
        const int F = nt * 4 + nfl;
        const int kidx = kt * 2 + k0l;
        *(uint4*)(dstE + ((size_t)(F * K32 + kidx) << 9) + l * 8) = p.v;
    }
}

// ---- per-block (expert, tile) mapping from counts prefix ----
__device__ inline bool find_tile(const int* __restrict__ counts, int tflat,
                                 int& e, int& t0, int& off, int& n_e)
{
    int cum = 0, offacc = 0; e = -1;
#pragma unroll
    for (int i = 0; i < E_; ++i) {
        const int c = counts[i];
        const int t = (c + 31) >> 5;
        if (e < 0 && tflat < cum + t) { e = i; t0 = (tflat - cum) << 5; off = offacc; n_e = c; }
        cum += t; offacc += c;
    }
    return e >= 0;
}

// ---- stage1: H[slot][h] = relu(Xbf[tok] @ W1 + b1), streaming MFMA ----
__global__ __launch_bounds__(256) void stage1_kernel(
    const unsigned short* __restrict__ xbf,
    const unsigned short* __restrict__ W1S, const float* __restrict__ b1,
    const int* __restrict__ counts, const int* __restrict__ lists,
    unsigned short* __restrict__ Hbuf)
{
    const int nb = blockIdx.x & 3;
    const int tflat = blockIdx.x >> 2;
    int e, t0, off, n_e;
    if (!find_tile(counts, tflat, e, t0, off, n_e)) return;
    const int mact = min(32, n_e - t0);
    __shared__ int tks[32];
    const int tid = threadIdx.x;
    if (tid < 32) tks[tid] = lists[e * NT_ + t0 + min(tid, mact - 1)];
    __syncthreads();

    const int wave = tid >> 6, lane = tid & 63, m = lane & 15, g = lane >> 4;
    const int colbase = nb * 256 + wave * 64;

    const unsigned short* a0p = xbf + ((size_t)tks[m] << 9) + (g << 3);
    const unsigned short* a1p = xbf + ((size_t)tks[16 + m] << 9) + (g << 3);
    const unsigned short* Bb = W1S + ((size_t)e << 19)
                             + ((size_t)(nb * 16 + wave * 4) << 13) + (lane << 3);

    f32x4 acc[2][4];
#pragma unroll
    for (int i = 0; i < 2; ++i)
#pragma unroll
        for (int f = 0; f < 4; ++f) acc[i][f] = (f32x4){0.f, 0.f, 0.f, 0.f};

#pragma unroll 2
    for (int kk = 0; kk < 16; ++kk) {
        const short8v a0 = *(const short8v*)(a0p + (kk << 5));
        const short8v a1 = *(const short8v*)(a1p + (kk << 5));
        const short8v b0  = *(const short8v*)(Bb + (kk << 9));
        const short8v b1v = *(const short8v*)(Bb + (1 << 13) + (kk << 9));
        const short8v b2v = *(const short8v*)(Bb + (2 << 13) + (kk << 9));
        const short8v b3  = *(const short8v*)(Bb + (3 << 13) + (kk << 9));
        acc[0][0] = __builtin_amdgcn_mfma_f32_16x16x32_bf16(a0, b0,  acc[0][0], 0, 0, 0);
        acc[1][0] = __builtin_amdgcn_mfma_f32_16x16x32_bf16(a1, b0,  acc[1][0], 0, 0, 0);
        acc[0][1] = __builtin_amdgcn_mfma_f32_16x16x32_bf16(a0, b1v, acc[0][1], 0, 0, 0);
        acc[1][1] = __builtin_amdgcn_mfma_f32_16x16x32_bf16(a1, b1v, acc[1][1], 0, 0, 0);
        acc[0][2] = __builtin_amdgcn_mfma_f32_16x16x32_bf16(a0, b2v, acc[0][2], 0, 0, 0);
        acc[1][2] = __builtin_amdgcn_mfma_f32_16x16x32_bf16(a1, b2v, acc[1][2], 0, 0, 0);
        acc[0][3] = __builtin_amdgcn_mfma_f32_16x16x32_bf16(a0, b3,  acc[0][3], 0, 0, 0);
        acc[1][3] = __builtin_amdgcn_mfma_f32_16x16x32_bf16(a1, b3,  acc[1][3], 0, 0, 0);
    }

#pragma unroll
    for (int f = 0; f < 4; ++f) {
        const int col = colbase + f * 16 + m;
        const float bias = b1[(e << 10) + col];
#pragma unroll
        for (int i = 0; i < 2; ++i)
#pragma unroll
            for (int r = 0; r < 4; ++r) {
                const int row = i * 16 + g * 4 + r;
                if (row < mact)
                    Hbuf[((size_t)(off + t0 + row) << 10) + col] =
                        f2bf(fmaxf(acc[i][f][r] + bias, 0.f));
            }
    }
}

// ---- stage2: out[tok] += gate * (H[slot] @ W2 + b2), streaming MFMA ----
__global__ __launch_bounds__(256) void stage2_kernel(
    const unsigned short* __restrict__ Hbuf,
    const unsigned short* __restrict__ W2S, const float* __restrict__ b2,
    const int* __restrict__ counts, const int* __restrict__ lists,
    const float* __restrict__ gvals, float* __restrict__ out)
{
    const int nb = blockIdx.x & 1;
    const int tflat = blockIdx.x >> 1;
    int e, t0, off, n_e;
    if (!find_tile(counts, tflat, e, t0, off, n_e)) return;
    const int mact = min(32, n_e - t0);
    __shared__ int tks[32];
    __shared__ float gsh[32];
    const int tid = threadIdx.x;
    if (tid < 32) {
        const int idx = min(tid, mact - 1);
        tks[tid] = lists[e * NT_ + t0 + idx];
        gsh[tid] = gvals[e * NT_ + t0 + idx];
    }
    __syncthreads();

    const int wave = tid >> 6, lane = tid & 63, m = lane & 15, g = lane >> 4;
    const int colbase = nb * 256 + wave * 64;

    const unsigned short* a0p = Hbuf + ((size_t)(off + t0 + m) << 10) + (g << 3);
    const unsigned short* a1p = Hbuf + ((size_t)(off + t0 + 16 + m) << 10) + (g << 3);
    const unsigned short* Bb = W2S + ((size_t)e << 19)
                             + ((size_t)(nb * 16 + wave * 4) << 14) + (lane << 3);

    f32x4 acc[2][4];
#pragma unroll
    for (int i = 0; i < 2; ++i)
#pragma unroll
        for (int f = 0; f < 4; ++f) acc[i][f] = (f32x4){0.f, 0.f, 0.f, 0.f};

#pragma unroll 2
    for (int kk = 0; kk < 32; ++kk) {
        const short8v a0 = *(const short8v*)(a0p + (kk << 5));
        const short8v a1 = *(const short8v*)(a1p + (kk << 5));
        const short8v b0  = *(const short8v*)(Bb + (kk << 9));
        const short8v b1v = *(const short8v*)(Bb + (1 << 14) + (kk << 9));
        const short8v b2v = *(const short8v*)(Bb + (2 << 14) + (kk << 9));
        const short8v b3  = *(const short8v*)(Bb + (3 << 14) + (kk << 9));
        acc[0][0] = __builtin_amdgcn_mfma_f32_16x16x32_bf16(a0, b0,  acc[0][0], 0, 0, 0);
        acc[1][0] = __builtin_amdgcn_mfma_f32_16x16x32_bf16(a1, b0,  acc[1][0], 0, 0, 0);
        acc[0][1] = __builtin_amdgcn_mfma_f32_16x16x32_bf16(a0, b1v, acc[0][1], 0, 0, 0);
        acc[1][1] = __builtin_amdgcn_mfma_f32_16x16x32_bf16(a1, b1v, acc[1][1], 0, 0, 0);
        acc[0][2] = __builtin_amdgcn_mfma_f32_16x16x32_bf16(a0, b2v, acc[0][2], 0, 0, 0);
        acc[1][2] = __builtin_amdgcn_mfma_f32_16x16x32_bf16(a1, b2v, acc[1][2], 0, 0, 0);
        acc[0][3] = __builtin_amdgcn_mfma_f32_16x16x32_bf16(a0, b3,  acc[0][3], 0, 0, 0);
        acc[1][3] = __builtin_amdgcn_mfma_f32_16x16x32_bf16(a1, b3,  acc[1][3], 0, 0, 0);
    }

#pragma unroll
    for (int f = 0; f < 4; ++f) {
        const int col = colbase + f * 16 + m;
        const float bias = b2[(e << 9) + col];
#pragma unroll
        for (int i = 0; i < 2; ++i)
#pragma unroll
            for (int r = 0; r < 4; ++r) {
                const int row = i * 16 + g * 4 + r;
                if (row < mact)
                    atomicAdd(out + ((size_t)tks[row] << 9) + col,
                              (acc[i][f][r] + bias) * gsh[row]);
            }
    }
}

// ======================= TIER B/C fallbacks =======================

__global__ __launch_bounds__(256) void gating_kernel(
    const float* __restrict__ x, const int* __restrict__ mask,
    const float* __restrict__ wg, int* __restrict__ counts,
    int* __restrict__ lists, float* __restrict__ gvals)
{
    const int wave = threadIdx.x >> 6;
    const int lane = threadIdx.x & 63;
    const int t = blockIdx.x * 4 + wave;
    const float* xr = x + (size_t)t * D_;
    float acc[E_];
#pragma unroll
    for (int e = 0; e < E_; ++e) acc[e] = 0.f;
    for (int d = lane; d < D_; d += 64) {
        const float xv = xr[d];
        const float* wr = wg + (size_t)d * E_;
#pragma unroll
        for (int e = 0; e < E_; ++e) acc[e] += xv * wr[e];
    }
#pragma unroll
    for (int e = 0; e < E_; ++e) {
        float v = acc[e];
#pragma unroll
        for (int off = 32; off > 0; off >>= 1) v += __shfl_down(v, off, 64);
        acc[e] = v;
    }
    if (lane == 0 && mask[t] != 0) {
        int i0 = 0; float v0 = acc[0];
#pragma unroll
        for (int e = 1; e < E_; ++e) if (acc[e] > v0) { v0 = acc[e]; i0 = e; }
        int i1 = -1; float v1 = -INFINITY;
#pragma unroll
        for (int e = 0; e < E_; ++e) if (e != i0 && acc[e] > v1) { v1 = acc[e]; i1 = e; }
        const float ex = __expf(v1 - v0);
        const float denom = 1.f + ex;
        const int p0 = atomicAdd(&counts[i0], 1);
        lists[i0 * NT_ + p0] = t; gvals[i0 * NT_ + p0] = 1.f / denom;
        const int p1 = atomicAdd(&counts[i1], 1);
        lists[i1 * NT_ + p1] = t; gvals[i1 * NT_ + p1] = ex / denom;
    }
}

__global__ __launch_bounds__(256) void init_out_kernel(
    const float* __restrict__ x, float* __restrict__ out)
{
    const size_t i = (size_t)blockIdx.x * blockDim.x + threadIdx.x;
    ((float4*)out)[i] = ((const float4*)x)[i];
}

__global__ __launch_bounds__(256) void transpose_cvt(
    const float* __restrict__ src, unsigned short* __restrict__ dst, int R, int C)
{
    __shared__ unsigned short t[64][72];
    const float* s = src + (size_t)blockIdx.z * R * C;
    unsigned short* d = dst + (size_t)blockIdx.z * R * C;
    const int r0 = blockIdx.y * 64, c0 = blockIdx.x * 64;
    const int tc = threadIdx.x & 63;
    const int tr = threadIdx.x >> 6;
#pragma unroll
    for (int i = 0; i < 16; ++i) {
        const int r = tr + i * 4;
        t[r][tc] = f2bf(s[(size_t)(r0 + r) * C + c0 + tc]);
    }
    __syncthreads();
    const int c = threadIdx.x >> 2;
    const int ch = threadIdx.x & 3;
#pragma unroll
    for (int half = 0; half < 2; ++half) {
        union { unsigned short u[8]; uint4 v; } p;
#pragma unroll
        for (int k = 0; k < 8; ++k) p.u[k] = t[ch * 16 + half * 8 + k][c];
        *(uint4*)(d + (size_t)(c0 + c) * R + r0 + ch * 16 + half * 8) = p.v;
    }
}

__global__ __launch_bounds__(256) void expert_mfma(
    const float* __restrict__ x,
    const unsigned short* __restrict__ W1T, const float* __restrict__ b1,
    const unsigned short* __restrict__ W2T, const float* __restrict__ b2,
    const int* __restrict__ counts, const int* __restrict__ lists,
    const float* __restrict__ gvals, float* __restrict__ out)
{
    __shared__ unsigned short Xs[TM * D_];
    __shared__ unsigned short Hs[TM * H_];
    __shared__ int   tks[TM];
    __shared__ float gs[TM];

    const int bi = blockIdx.x;
    const int e = bi & 7;
    const int t0 = (bi >> 3) * TM;
    const int n = counts[e];
    if (t0 >= n) return;
    const int tid = threadIdx.x;
    const int mact = min(TM, n - t0);
    const int wave = tid >> 6;
    const int lane = tid & 63;
    const int m = lane & 15;
    const int g = lane >> 4;
    char* XsC = (char*)Xs;
    char* HsC = (char*)Hs;

    if (tid < TM) {
        if (tid < mact) {
            tks[tid] = lists[e * NT_ + t0 + tid];
            gs[tid]  = gvals[e * NT_ + t0 + tid];
        } else { tks[tid] = 0; gs[tid] = 0.f; }
    }
    __syncthreads();

    for (int idx = tid; idx < TM * (D_ / 8); idx += 256) {
        const int mm = idx >> 6;
        const int c8 = idx & 63;
        union { unsigned short u[8]; uint4 v; } p;
        if (mm < mact) {
            const float4* xr = (const float4*)(x + (size_t)tks[mm] * D_);
            const float4 v0 = xr[c8 * 2], v1 = xr[c8 * 2 + 1];
            p.u[0]=f2bf(v0.x); p.u[1]=f2bf(v0.y); p.u[2]=f2bf(v0.z); p.u[3]=f2bf(v0.w);
            p.u[4]=f2bf(v1.x); p.u[5]=f2bf(v1.y); p.u[6]=f2bf(v1.z); p.u[7]=f2bf(v1.w);
        } else {
            p.v = make_uint4(0, 0, 0, 0);
        }
        const int off = mm * (D_ * 2) + c8 * 16;
        *(uint4*)(XsC + (off ^ ((mm & 7) << 4))) = p.v;
    }
    __syncthreads();

    const int nbase = wave * 256;
    f32x4 acc1[16];
#pragma unroll
    for (int f = 0; f < 16; ++f) acc1[f] = (f32x4){0.f, 0.f, 0.f, 0.f};

    for (int k0 = 0; k0 < D_; k0 += 32) {
        const int aoff = m * (D_ * 2) + k0 * 2 + g * 16;
        const short8v a = *(const short8v*)(XsC + (aoff ^ ((m & 7) << 4)));
#pragma unroll
        for (int f = 0; f < 16; ++f) {
            const unsigned short* bp = W1T + (((size_t)(e << 10) + nbase + f * 16 + m) << 9) + k0 + g * 8;
            const short8v b = *(const short8v*)bp;
            acc1[f] = __builtin_amdgcn_mfma_f32_16x16x32_bf16(a, b, acc1[f], 0, 0, 0);
        }
    }
#pragma unroll
    for (int f = 0; f < 16; ++f) {
        const int nn = nbase + f * 16 + m;
        const float bias = b1[(e << 10) + nn];
#pragma unroll
        for (int r = 0; r < 4; ++r) {
            const int mm = g * 4 + r;
            const unsigned short hv = f2bf(fmaxf(acc1[f][r] + bias, 0.f));
            const int off = mm * (H_ * 2) + nn * 2;
            *(unsigned short*)(HsC + (off ^ ((mm & 7) << 4))) = hv;
        }
    }
    __syncthreads();

    const int obase = wave * 128;
    f32x4 acc2[8];
#pragma unroll
    for (int f = 0; f < 8; ++f) acc2[f] = (f32x4){0.f, 0.f, 0.f, 0.f};

    for (int k0 = 0; k0 < H_; k0 += 32) {
        const int aoff = m * (H_ * 2) + k0 * 2 + g * 16;
        const short8v a = *(const short8v*)(HsC + (aoff ^ ((m & 7) << 4)));
#pragma unroll
        for (int f = 0; f < 8; ++f) {
            const unsigned short* bp = W2T + (((size_t)(e << 9) + obase + f * 16 + m) << 10) + k0 + g * 8;
            const short8v b = *(const short8v*)bp;
            acc2[f] = __builtin_amdgcn_mfma_f32_16x16x32_bf16(a, b, acc2[f], 0, 0, 0);
        }
    }
#pragma unroll
    for (int f = 0; f < 8; ++f) {
        const int o = obase + f * 16 + m;
        const float bias = b2[(e << 9) + o];
#pragma unroll
        for (int r = 0; r < 4; ++r) {
            const int mm = g * 4 + r;
            const float gv = gs[mm];
            if (gv != 0.f)
                atomicAdd(out + (size_t)tks[mm] * D_ + o, (acc2[f][r] + bias) * gv);
        }
    }
}

__global__ __launch_bounds__(256) void expert_fp32(
    const float* __restrict__ x,
    const float* __restrict__ W1, const float* __restrict__ b1,
    const float* __restrict__ W2, const float* __restrict__ b2,
    const int* __restrict__ counts, const int* __restrict__ lists,
    const float* __restrict__ gvals, float* __restrict__ out)
{
    __shared__ float Xs[TM][D_];
    __shared__ float Hs[TM][H_];
    __shared__ int   tks[TM];
    __shared__ float gs[TM];

    const int e  = blockIdx.y;
    const int n  = counts[e];
    const int t0 = blockIdx.x * TM;
    if (t0 >= n) return;
    const int tid  = threadIdx.x;
    const int mact = min(TM, n - t0);

    if (tid < TM) {
        if (tid < mact) {
            tks[tid] = lists[e * NT_ + t0 + tid];
            gs[tid]  = gvals[e * NT_ + t0 + tid];
        } else { tks[tid] = 0; gs[tid] = 0.f; }
    }
    __syncthreads();
    for (int idx = tid; idx < TM * (D_ / 4); idx += 256) {
        const int mm = idx >> 7, c = idx & 127;
        float4 v = make_float4(0.f, 0.f, 0.f, 0.f);
        if (mm < mact) v = ((const float4*)(x + (size_t)tks[mm] * D_))[c];
        ((float4*)&Xs[mm][0])[c] = v;
    }
    __syncthreads();
    const float* W1e = W1 + (size_t)e * D_ * H_;
    float acc[4][TM];
#pragma unroll
    for (int jj = 0; jj < 4; ++jj)
#pragma unroll
        for (int mm = 0; mm < TM; ++mm) acc[jj][mm] = 0.f;
    for (int d4 = 0; d4 < D_ / 4; ++d4) {
        float w[4][4];
#pragma unroll
        for (int dd = 0; dd < 4; ++dd) {
            const float* wp = W1e + (size_t)(d4 * 4 + dd) * H_ + tid;
#pragma unroll
            for (int jj = 0; jj < 4; ++jj) w[dd][jj] = wp[jj * 256];
        }
#pragma unroll
        for (int mm = 0; mm < TM; ++mm) {
            const float4 xv = ((const float4*)&Xs[mm][0])[d4];
            const float* xp = &xv.x;
#pragma unroll
            for (int dd = 0; dd < 4; ++dd)
#pragma unroll
                for (int jj = 0; jj < 4; ++jj)
                    acc[jj][mm] = fmaf(xp[dd], w[dd][jj], acc[jj][mm]);
        }
    }
#pragma unroll
    for (int jj = 0; jj < 4; ++jj) {
        const int j = jj * 256 + tid;
        const float bv = b1[e * H_ + j];
#pragma unroll
        for (int mm = 0; mm < TM; ++mm) Hs[mm][j] = fmaxf(acc[jj][mm] + bv, 0.f);
    }
    __syncthreads();
    const float* W2e = W2 + (size_t)e * H_ * D_;
    float acc2[2][TM];
#pragma unroll
    for (int oo = 0; oo < 2; ++oo)
#pragma unroll
        for (int mm = 0; mm < TM; ++mm) acc2[oo][mm] = 0.f;
    for (int j4 = 0; j4 < H_ / 4; ++j4) {
        float w[4][2];
#pragma unroll
        for (int dd = 0; dd < 4; ++dd) {
            const float* wp = W2e + (size_t)(j4 * 4 + dd) * D_ + tid;
#pragma unroll
            for (int oo = 0; oo < 2; ++oo) w[dd][oo] = wp[oo * 256];
        }
#pragma unroll
        for (int mm = 0; mm < TM; ++mm) {
            const float4 hv = ((const float4*)&Hs[mm][0])[j4];
            const float* hp = &hv.x;
#pragma unroll
            for (int dd = 0; dd < 4; ++dd)
#pragma unroll
                for (int oo = 0; oo < 2; ++oo)
                    acc2[oo][mm] = fmaf(hp[dd], w[dd][oo], acc2[oo][mm]);
        }
    }
#pragma unroll
    for (int oo = 0; oo < 2; ++oo) {
        const int o = oo * 256 + tid;
        const float bv = b2[e * D_ + o];
        for (int mm = 0; mm < mact; ++mm)
            atomicAdd(out + (size_t)tks[mm] * D_ + o, (acc2[oo][mm] + bv) * gs[mm]);
    }
}

// ======================= host launcher =======================

extern "C" void kernel_launch(void* const* d_in, const int* in_sizes, int n_in,
                              void* d_out, int out_size, void* d_ws, size_t ws_size,
                              hipStream_t stream)
{
    const float* x    = (const float*)d_in[0];
    const int*   mask = (const int*)d_in[1];
    const float* wg   = (const float*)d_in[2];
    const float* W1   = (const float*)d_in[3];
    const float* b1   = (const float*)d_in[4];
    const float* W2   = (const float*)d_in[5];
    const float* b2   = (const float*)d_in[6];
    float* out = (float*)d_out;

    char* ws = (char*)d_ws;
    int*   counts = (int*)ws;                       // 32 B
    int*   lists  = (int*)(ws + 256);               // 128 KB
    float* gvals  = (float*)(ws + 256 + 131072);    // 128 KB

    // Tier A layout
    uchar2* tokE = (uchar2*)(ws + 0x48000);                             // 8 KB
    float2* tokG = (float2*)(ws + 0x50000);                             // 32 KB
    unsigned short* xbf  = (unsigned short*)(ws + 0x60000);             // 4 MB
    unsigned short* W1Sa = (unsigned short*)(ws + 0x480000);            // 8 MB
    unsigned short* W2Sa = (unsigned short*)(ws + 0xC80000);            // 8 MB
    unsigned short* Hbuf = (unsigned short*)(ws + 0x1480000);           // 16.5 MB
    const size_t needA = 0x1480000 + (size_t)8448 * 1024 * 2;           // ~38.8 MB

    const size_t wt_bytes = (size_t)E_ * D_ * H_ * 2;
    const size_t needB = 524288 + 2 * wt_bytes;                         // ~17.3 MB

    if (ws_size >= needA) {
        prep0g_kernel<<<1024, 256, 0, stream>>>(x, mask, wg, out, xbf, tokE, tokG);
        prep1_kernel<<<2049, 256, 0, stream>>>(W1, W2, W1Sa, W2Sa,
                                               tokE, tokG, counts, lists, gvals);
        stage1_kernel<<<264 * 4, 256, 0, stream>>>(xbf, W1Sa, b1, counts, lists, Hbuf);
        stage2_kernel<<<264 * 2, 256, 0, stream>>>(Hbuf, W2Sa, b2, counts, lists, gvals, out);
    } else if (ws_size >= needB) {
        unsigned short* W1T = (unsigned short*)(ws + 524288);
        unsigned short* W2T = (unsigned short*)(ws + 524288 + wt_bytes);
        hipMemsetAsync(counts, 0, E_ * sizeof(int), stream);
        gating_kernel<<<NT_ / 4, 256, 0, stream>>>(x, mask, wg, counts, lists, gvals);
        init_out_kernel<<<(NT_ * D_) / 4 / 256, 256, 0, stream>>>(x, out);
        transpose_cvt<<<dim3(H_ / 64, D_ / 64, E_), 256, 0, stream>>>(W1, W1T, D_, H_);
        transpose_cvt<<<dim3(D_ / 64, H_ / 64, E_), 256, 0, stream>>>(W2, W2T, H_, D_);
        expert_mfma<<<(NT_ / TM) * E_, 256, 0, stream>>>(x, W1T, b1, W2T, b2,
                                                         counts, lists, gvals, out);
    } else {
        hipMemsetAsync(counts, 0, E_ * sizeof(int), stream);
        gating_kernel<<<NT_ / 4, 256, 0, stream>>>(x, mask, wg, counts, lists, gvals);
        init_out_kernel<<<(NT_ * D_) / 4 / 256, 256, 0, stream>>>(x, out);
        expert_fp32<<<dim3(NT_ / TM, E_), 256, 0, stream>>>(x, W1, b1, W2, b2,
                                                            counts, lists, gvals, out);
    }
}